// Round 1
// baseline (2854.071 us; speedup 1.0000x reference)
//
#include <hip/hip_runtime.h>
#include <math.h>

// Problem constants
#define BB 2
#define CC 128
#define HH 64
#define WW 64
#define LL 4096      // H*W
#define DI 256       // D_INNER
#define NS 16        // D_STATE
#define KK 4         // scan directions
#define OC1 42       // C // 3

__device__ __forceinline__ float sigmoidf_(float x) { return 1.f / (1.f + __expf(-x)); }
__device__ __forceinline__ float siluf_(float x)    { return x * sigmoidf_(x); }
__device__ __forceinline__ float softplusf_(float x){ return x > 20.f ? x : log1pf(__expf(x)); }

// ---------------------------------------------------------------------------
// K1: LN1 over C at each (b,p), then in_proj (512x128). 16 positions/block.
// Writes xcin (B,L,256) and z (B,L,256).
// ---------------------------------------------------------------------------
__global__ __launch_bounds__(256) void k1_ln_inproj(
    const float* __restrict__ inp, const float* __restrict__ g, const float* __restrict__ b,
    const float* __restrict__ wproj, float* __restrict__ xcin, float* __restrict__ zbuf) {
  __shared__ float sx[16][132];
  __shared__ float smu[16], srs[16];
  const int tid = threadIdx.x;
  const int bb = blockIdx.x >> 8;             // 256 blocks per batch
  const int pbase = (blockIdx.x & 255) << 4;  // 16 positions

  for (int idx = tid; idx < 16 * CC; idx += 256) {
    int c = idx >> 4, pl = idx & 15;
    sx[pl][c] = inp[((size_t)bb * CC + c) * LL + pbase + pl];
  }
  __syncthreads();
  {
    int pl = tid >> 4, j = tid & 15;
    float s = 0.f, s2 = 0.f;
    for (int c = j; c < CC; c += 16) { float v = sx[pl][c]; s += v; s2 += v * v; }
#pragma unroll
    for (int m = 1; m < 16; m <<= 1) { s += __shfl_xor(s, m); s2 += __shfl_xor(s2, m); }
    if (j == 0) {
      float mu = s * (1.f / CC);
      smu[pl] = mu;
      srs[pl] = rsqrtf(s2 * (1.f / CC) - mu * mu + 1e-5f);
    }
  }
  __syncthreads();
  for (int idx = tid; idx < 16 * CC; idx += 256) {
    int c = idx >> 4, pl = idx & 15;
    sx[pl][c] = (sx[pl][c] - smu[pl]) * srs[pl] * g[c] + b[c];
  }
  __syncthreads();

  float acc0[16], acc1[16];
#pragma unroll
  for (int pl = 0; pl < 16; pl++) { acc0[pl] = 0.f; acc1[pl] = 0.f; }
  const float4* w0 = (const float4*)(wproj + (size_t)tid * CC);          // xc row
  const float4* w1 = (const float4*)(wproj + (size_t)(tid + 256) * CC);  // z row
  for (int i = 0; i < CC / 4; i++) {
    float4 wa = w0[i], wb = w1[i];
#pragma unroll
    for (int pl = 0; pl < 16; pl++) {
      float4 xv = *(const float4*)&sx[pl][i * 4];
      acc0[pl] += wa.x * xv.x + wa.y * xv.y + wa.z * xv.z + wa.w * xv.w;
      acc1[pl] += wb.x * xv.x + wb.y * xv.y + wb.z * xv.z + wb.w * xv.w;
    }
  }
#pragma unroll
  for (int pl = 0; pl < 16; pl++) {
    size_t base = ((size_t)bb * LL + pbase + pl) * DI + tid;
    xcin[base] = acc0[pl];
    zbuf[base] = acc1[pl];
  }
}

// ---------------------------------------------------------------------------
// K2: depthwise 3x3 conv + bias + silu.  (B,L,256) -> (B,L,256)
// ---------------------------------------------------------------------------
__global__ __launch_bounds__(256) void k2_dwconv(
    const float* __restrict__ xcin, const float* __restrict__ cw, const float* __restrict__ cb,
    float* __restrict__ xconv) {
  const int p = blockIdx.x & (LL - 1);
  const int bb = blockIdx.x >> 12;
  const int hh = p >> 6, ww = p & 63;
  const int d = threadIdx.x;
  float acc = cb[d];
#pragma unroll
  for (int kh = 0; kh < 3; kh++) {
    int r = hh + kh - 1;
    if (r < 0 || r >= HH) continue;
#pragma unroll
    for (int kw = 0; kw < 3; kw++) {
      int cc2 = ww + kw - 1;
      if (cc2 < 0 || cc2 >= WW) continue;
      acc += cw[d * 9 + kh * 3 + kw] * xcin[((size_t)bb * LL + r * WW + cc2) * DI + d];
    }
  }
  xconv[((size_t)bb * LL + p) * DI + d] = siluf_(acc);
}

// ---------------------------------------------------------------------------
// K3: x_proj (4x40x256) per position -> dtr (LDS), Bs/Cs -> BCbuf (B,4,L,32);
//     then dt GEMM (8 ranks) + softplus -> dts (B,4,L,256). 16 positions/block.
// ---------------------------------------------------------------------------
__global__ __launch_bounds__(256) void k3_proj(
    const float* __restrict__ xconv, const float* __restrict__ xpw,
    const float* __restrict__ dtw, const float* __restrict__ dtb,
    float* __restrict__ BCbuf, float* __restrict__ dts) {
  __shared__ float sv[16][260];
  __shared__ float sdtr[16][KK][8];
  const int tid = threadIdx.x;
  const int bb = blockIdx.x >> 8;
  const int pbase = (blockIdx.x & 255) << 4;

  for (int idx = tid; idx < 16 * DI; idx += 256) {
    int d = idx & 255, pl = idx >> 8;
    sv[pl][d] = xconv[((size_t)bb * LL + pbase + pl) * DI + d];
  }
  __syncthreads();

  if (tid < 160) {
    int k = tid / 40, c = tid % 40;
    const float4* wp = (const float4*)(xpw + ((size_t)k * 40 + c) * DI);
    float acc[16];
#pragma unroll
    for (int pl = 0; pl < 16; pl++) acc[pl] = 0.f;
    for (int i = 0; i < DI / 4; i++) {
      float4 wv = wp[i];
#pragma unroll
      for (int pl = 0; pl < 16; pl++) {
        float4 xv = *(const float4*)&sv[pl][i * 4];
        acc[pl] += wv.x * xv.x + wv.y * xv.y + wv.z * xv.z + wv.w * xv.w;
      }
    }
#pragma unroll
    for (int pl = 0; pl < 16; pl++) {
      if (c < 8) sdtr[pl][k][c] = acc[pl];
      else BCbuf[(((size_t)bb * KK + k) * LL + pbase + pl) * 32 + (c - 8)] = acc[pl];
    }
  }
  __syncthreads();

  for (int k = 0; k < KK; k++) {
    const float4* wr = (const float4*)(dtw + ((size_t)k * DI + tid) * 8);
    float4 wv0 = wr[0], wv1 = wr[1];
    float base = dtb[k * DI + tid];
#pragma unroll 4
    for (int pl = 0; pl < 16; pl++) {
      const float* dr = sdtr[pl][k];
      float acc = base + wv0.x * dr[0] + wv0.y * dr[1] + wv0.z * dr[2] + wv0.w * dr[3]
                       + wv1.x * dr[4] + wv1.y * dr[5] + wv1.z * dr[6] + wv1.w * dr[7];
      dts[(((size_t)bb * KK + k) * LL + pbase + pl) * DI + tid] = softplusf_(acc);
    }
  }
}

// ---------------------------------------------------------------------------
// K4: selective scan. One lane per (d,n); 16-lane butterfly for y = sum_n h*C.
// All 4 directions read AND write at the spatial position visited at step i,
// so the later combine is a plain sum over k.  grid = B*K*(D/16) = 128 blocks.
// ---------------------------------------------------------------------------
__global__ __launch_bounds__(256) void k4_scan(
    const float* __restrict__ xconv, const float* __restrict__ dts,
    const float* __restrict__ BCbuf, const float* __restrict__ A_logs,
    const float* __restrict__ Ds, float* __restrict__ ys) {
  const int tid = threadIdx.x;
  const int n = tid & 15, dl = tid >> 4;
  const int dg = blockIdx.x & 15;
  const int k = (blockIdx.x >> 4) & 3;
  const int bb = blockIdx.x >> 6;
  const int d = dg * 16 + dl;

  const float a = -__expf(A_logs[((size_t)k * DI + d) * NS + n]);
  const float Dd = Ds[k * DI + d];
  const float* dts_bk = dts + ((size_t)(bb * KK + k)) * LL * DI;
  const float* bc_bk = BCbuf + ((size_t)(bb * KK + k)) * LL * 32;
  const float* x_b = xconv + (size_t)bb * LL * DI;
  float* ys_bk = ys + ((size_t)(bb * KK + k)) * LL * DI;

  float h = 0.f;
#pragma unroll 4
  for (int i = 0; i < LL; i++) {
    int pos;
    if (k == 0)      pos = i;
    else if (k == 1) pos = ((i & 63) << 6) | (i >> 6);
    else if (k == 2) pos = (LL - 1) - i;
    else { int j = (LL - 1) - i; pos = ((j & 63) << 6) | (j >> 6); }

    float dt = dts_bk[(size_t)pos * DI + d];
    float xv = x_b[(size_t)pos * DI + d];
    float Bv = bc_bk[pos * 32 + n];
    float Cv = bc_bk[pos * 32 + 16 + n];

    h = __expf(dt * a) * h + (dt * xv) * Bv;
    float t = h * Cv;
    t += __shfl_xor(t, 1);
    t += __shfl_xor(t, 2);
    t += __shfl_xor(t, 4);
    t += __shfl_xor(t, 8);
    if (n == 0) ys_bk[(size_t)pos * DI + d] = t + xv * Dd;
  }
}

// ---------------------------------------------------------------------------
// K5: sum 4 directions, out_norm LN(256), * silu(z), out_proj (128x256),
//     + input*skip_scale -> xres (B,L,128); then LN2 -> ln2 (B,128,L) NCHW.
//     8 positions/block.
// ---------------------------------------------------------------------------
__global__ __launch_bounds__(256) void k5_combine(
    const float* __restrict__ ys, const float* __restrict__ zbuf,
    const float* __restrict__ ong, const float* __restrict__ onb,
    const float* __restrict__ opw, const float* __restrict__ inp,
    const float* __restrict__ sk, const float* __restrict__ g2, const float* __restrict__ b2,
    float* __restrict__ xres, float* __restrict__ ln2) {
  __shared__ float sy[8][260];
  __shared__ float sr[8][132];
  __shared__ float smu[8], srs[8];
  const int tid = threadIdx.x;
  const int bb = blockIdx.x >> 9;             // 512 blocks per batch
  const int pbase = (blockIdx.x & 511) << 3;  // 8 positions

  for (int idx = tid; idx < 8 * DI; idx += 256) {
    int d = idx & 255, pl = idx >> 8;
    size_t o0 = (((size_t)bb * KK + 0) * LL + pbase + pl) * DI + d;
    const size_t st = (size_t)LL * DI;
    sy[pl][d] = ys[o0] + ys[o0 + st] + ys[o0 + 2 * st] + ys[o0 + 3 * st];
  }
  __syncthreads();
  {
    int pl = tid >> 5, j = tid & 31;
    float s = 0.f, s2 = 0.f;
    for (int d = j; d < DI; d += 32) { float v = sy[pl][d]; s += v; s2 += v * v; }
#pragma unroll
    for (int m = 1; m < 32; m <<= 1) { s += __shfl_xor(s, m); s2 += __shfl_xor(s2, m); }
    if (j == 0) {
      float mu = s * (1.f / DI);
      smu[pl] = mu;
      srs[pl] = rsqrtf(s2 * (1.f / DI) - mu * mu + 1e-5f);
    }
  }
  __syncthreads();
  for (int idx = tid; idx < 8 * DI; idx += 256) {
    int d = idx & 255, pl = idx >> 8;
    float zv = zbuf[((size_t)bb * LL + pbase + pl) * DI + d];
    sy[pl][d] = ((sy[pl][d] - smu[pl]) * srs[pl] * ong[d] + onb[d]) * siluf_(zv);
  }
  __syncthreads();
  {
    const int c = tid & 127, plg = tid >> 7;
    float acc[4] = {0.f, 0.f, 0.f, 0.f};
    const float4* wr = (const float4*)(opw + (size_t)c * DI);
    for (int i = 0; i < DI / 4; i++) {
      float4 wv = wr[i];
#pragma unroll
      for (int q = 0; q < 4; q++) {
        float4 xv = *(const float4*)&sy[plg + 2 * q][i * 4];
        acc[q] += wv.x * xv.x + wv.y * xv.y + wv.z * xv.z + wv.w * xv.w;
      }
    }
#pragma unroll
    for (int q = 0; q < 4; q++) {
      int pl = plg + 2 * q;
      int p = pbase + pl;
      float r = inp[((size_t)bb * CC + c) * LL + p] * sk[c] + acc[q];
      xres[((size_t)bb * LL + p) * CC + c] = r;
      sr[pl][c] = r;
    }
  }
  __syncthreads();
  {
    int pl = tid >> 5, j = tid & 31;
    float s = 0.f, s2 = 0.f;
    for (int c = j; c < CC; c += 32) { float v = sr[pl][c]; s += v; s2 += v * v; }
#pragma unroll
    for (int m = 1; m < 32; m <<= 1) { s += __shfl_xor(s, m); s2 += __shfl_xor(s2, m); }
    if (j == 0) {
      float mu = s * (1.f / CC);
      smu[pl] = mu;
      srs[pl] = rsqrtf(s2 * (1.f / CC) - mu * mu + 1e-5f);
    }
  }
  __syncthreads();
  for (int idx = tid; idx < 8 * CC; idx += 256) {
    int pl = idx & 7, c = idx >> 3;
    ln2[((size_t)bb * CC + c) * LL + pbase + pl] =
        (sr[pl][c] - smu[pl]) * srs[pl] * g2[c] + b2[c];
  }
}

// ---------------------------------------------------------------------------
// K6: CAB conv1 3x3 (42 x 128) + exact GELU.  One (b,h) row per block.
// ---------------------------------------------------------------------------
__global__ __launch_bounds__(256) void k6_conv1(
    const float* __restrict__ ln2, const float* __restrict__ w1, const float* __restrict__ b1,
    float* __restrict__ t1) {
  __shared__ float sIn[16][3][68];
  const int tid = threadIdx.x;
  const int bb = blockIdx.x >> 6;
  const int hh = blockIdx.x & 63;
  const int wl = tid & 63, ocg = tid >> 6;
  float acc[11];
#pragma unroll
  for (int j = 0; j < 11; j++) acc[j] = 0.f;

  for (int icc = 0; icc < 8; icc++) {
    for (int idx = tid; idx < 16 * 3 * 66; idx += 256) {
      int wcol = idx % 66; int t = idx / 66; int kh = t % 3; int ic = t / 3;
      int r = hh + kh - 1, cc2 = wcol - 1;
      float v = 0.f;
      if (r >= 0 && r < HH && cc2 >= 0 && cc2 < WW)
        v = ln2[((size_t)bb * CC + icc * 16 + ic) * LL + r * WW + cc2];
      sIn[ic][kh][wcol] = v;
    }
    __syncthreads();
    for (int ic = 0; ic < 16; ic++) {
#pragma unroll
      for (int kh = 0; kh < 3; kh++) {
#pragma unroll
        for (int kw = 0; kw < 3; kw++) {
          float xv = sIn[ic][kh][wl + kw];
#pragma unroll
          for (int j = 0; j < 11; j++) {
            int oc = ocg + 4 * j;
            if (oc < OC1)
              acc[j] += w1[((size_t)oc * CC + icc * 16 + ic) * 9 + kh * 3 + kw] * xv;
          }
        }
      }
    }
    __syncthreads();
  }
#pragma unroll
  for (int j = 0; j < 11; j++) {
    int oc = ocg + 4 * j;
    if (oc < OC1) {
      float x = acc[j] + b1[oc];
      t1[((size_t)bb * OC1 + oc) * LL + hh * WW + wl] =
          0.5f * x * (1.f + erff(x * 0.70710678118654752f));
    }
  }
}

// ---------------------------------------------------------------------------
// K7: CAB conv2 3x3 (128 x 42) + bias.  One (b,h) row per block.
// ---------------------------------------------------------------------------
__global__ __launch_bounds__(256) void k7_conv2(
    const float* __restrict__ t1, const float* __restrict__ w2, const float* __restrict__ b2,
    float* __restrict__ t2) {
  __shared__ float sIn[14][3][68];
  const int tid = threadIdx.x;
  const int bb = blockIdx.x >> 6;
  const int hh = blockIdx.x & 63;
  const int wl = tid & 63, ocg = tid >> 6;
  float acc[32];
#pragma unroll
  for (int j = 0; j < 32; j++) acc[j] = 0.f;

  for (int icc = 0; icc < 3; icc++) {
    for (int idx = tid; idx < 14 * 3 * 66; idx += 256) {
      int wcol = idx % 66; int t = idx / 66; int kh = t % 3; int ic = t / 3;
      int r = hh + kh - 1, cc2 = wcol - 1;
      float v = 0.f;
      if (r >= 0 && r < HH && cc2 >= 0 && cc2 < WW)
        v = t1[((size_t)bb * OC1 + icc * 14 + ic) * LL + r * WW + cc2];
      sIn[ic][kh][wcol] = v;
    }
    __syncthreads();
    for (int ic = 0; ic < 14; ic++) {
#pragma unroll
      for (int kh = 0; kh < 3; kh++) {
#pragma unroll
        for (int kw = 0; kw < 3; kw++) {
          float xv = sIn[ic][kh][wl + kw];
#pragma unroll
          for (int j = 0; j < 32; j++)
            acc[j] += w2[((size_t)(ocg + 4 * j) * OC1 + icc * 14 + ic) * 9 + kh * 3 + kw] * xv;
        }
      }
    }
    __syncthreads();
  }
#pragma unroll
  for (int j = 0; j < 32; j++) {
    int oc = ocg + 4 * j;
    t2[((size_t)bb * CC + oc) * LL + hh * WW + wl] = acc[j] + b2[oc];
  }
}

// ---------------------------------------------------------------------------
// K8: per-(b,c) mean of t2 over L.
// ---------------------------------------------------------------------------
__global__ __launch_bounds__(256) void k8_mean(const float* __restrict__ t2,
                                               float* __restrict__ smean) {
  __shared__ float red[4];
  const int bc = blockIdx.x;
  const float* src = t2 + (size_t)bc * LL;
  float s = 0.f;
  for (int i = threadIdx.x; i < LL; i += 256) s += src[i];
#pragma unroll
  for (int m = 1; m < 64; m <<= 1) s += __shfl_xor(s, m);
  if ((threadIdx.x & 63) == 0) red[threadIdx.x >> 6] = s;
  __syncthreads();
  if (threadIdx.x == 0) smean[bc] = (red[0] + red[1] + red[2] + red[3]) * (1.f / LL);
}

// ---------------------------------------------------------------------------
// K9: channel attention MLP: relu(ca_w1 @ mean + b1) -> sigmoid(ca_w2 @ . + b2)
// ---------------------------------------------------------------------------
__global__ __launch_bounds__(128) void k9_ca(
    const float* __restrict__ smean, const float* __restrict__ w1, const float* __restrict__ b1,
    const float* __restrict__ w2, const float* __restrict__ b2, float* __restrict__ s3) {
  __shared__ float sm[128];
  __shared__ float mid[4];
  const int tid = threadIdx.x;
  const int bb = blockIdx.x;
  sm[tid] = smean[bb * CC + tid];
  __syncthreads();
  if (tid < 4) {
    float a = b1[tid];
    for (int c = 0; c < CC; c++) a += w1[tid * CC + c] * sm[c];
    mid[tid] = fmaxf(a, 0.f);
  }
  __syncthreads();
  float a = b2[tid];
#pragma unroll
  for (int m = 0; m < 4; m++) a += w2[tid * 4 + m] * mid[m];
  s3[bb * CC + tid] = sigmoidf_(a);
}

// ---------------------------------------------------------------------------
// K10: out[b][c][p] = xres[b][p][c]*skip_scale2[c] + t2[b][c][p]*s3[b][c]
// ---------------------------------------------------------------------------
__global__ __launch_bounds__(256) void k10_final(
    const float* __restrict__ xres, const float* __restrict__ t2,
    const float* __restrict__ s3, const float* __restrict__ sk2,
    float* __restrict__ out) {
  const int bc = blockIdx.x;
  const int bb = bc >> 7, c = bc & 127;
  const float ss = sk2[c], sv = s3[bc];
  const float* t2r = t2 + (size_t)bc * LL;
  float* outr = out + (size_t)bc * LL;
  for (int i = threadIdx.x; i < LL; i += 256)
    outr[i] = xres[((size_t)bb * LL + i) * CC + c] * ss + t2r[i] * sv;
}

// ---------------------------------------------------------------------------

extern "C" void kernel_launch(void* const* d_in, const int* in_sizes, int n_in,
                              void* d_out, int out_size, void* d_ws, size_t ws_size,
                              hipStream_t stream) {
  const float* input      = (const float*)d_in[0];
  const float* ln1_g      = (const float*)d_in[1];
  const float* ln1_b      = (const float*)d_in[2];
  const float* skip_scale = (const float*)d_in[3];
  const float* skip_scale2= (const float*)d_in[4];
  const float* ln2_g      = (const float*)d_in[5];
  const float* ln2_b      = (const float*)d_in[6];
  const float* in_proj_w  = (const float*)d_in[7];
  const float* conv_w     = (const float*)d_in[8];
  const float* conv_b     = (const float*)d_in[9];
  const float* x_proj_w   = (const float*)d_in[10];
  const float* dt_w       = (const float*)d_in[11];
  const float* dt_b       = (const float*)d_in[12];
  const float* A_logs     = (const float*)d_in[13];
  const float* Ds         = (const float*)d_in[14];
  const float* out_norm_g = (const float*)d_in[15];
  const float* out_norm_b = (const float*)d_in[16];
  const float* out_proj_w = (const float*)d_in[17];
  const float* cab_w1     = (const float*)d_in[18];
  const float* cab_b1     = (const float*)d_in[19];
  const float* cab_w2     = (const float*)d_in[20];
  const float* cab_b2     = (const float*)d_in[21];
  const float* ca_w1      = (const float*)d_in[22];
  const float* ca_b1      = (const float*)d_in[23];
  const float* ca_w2      = (const float*)d_in[24];
  const float* ca_b2      = (const float*)d_in[25];

  float* ws = (float*)d_ws;
  // workspace layout (floats); total ~27.6M floats = ~105 MB
  float* xcin  = ws;                                   // B*L*256
  float* zbuf  = xcin + (size_t)BB * LL * DI;          // B*L*256
  float* xconv = zbuf + (size_t)BB * LL * DI;          // B*L*256
  float* BCbuf = xconv + (size_t)BB * LL * DI;         // B*4*L*32
  float* dts   = BCbuf + (size_t)BB * KK * LL * 32;    // B*4*L*256
  float* ysb   = dts + (size_t)BB * KK * LL * DI;      // B*4*L*256
  float* xres  = ysb + (size_t)BB * KK * LL * DI;      // B*L*128
  float* ln2b  = xres + (size_t)BB * LL * CC;          // B*128*L
  float* t1b   = ln2b + (size_t)BB * CC * LL;          // B*42*L
  float* t2b   = t1b + (size_t)BB * OC1 * LL;          // B*128*L
  float* smean = t2b + (size_t)BB * CC * LL;           // B*128
  float* s3    = smean + BB * CC;                      // B*128

  k1_ln_inproj<<<BB * (LL / 16), 256, 0, stream>>>(input, ln1_g, ln1_b, in_proj_w, xcin, zbuf);
  k2_dwconv<<<BB * LL, 256, 0, stream>>>(xcin, conv_w, conv_b, xconv);
  k3_proj<<<BB * (LL / 16), 256, 0, stream>>>(xconv, x_proj_w, dt_w, dt_b, BCbuf, dts);
  k4_scan<<<BB * KK * (DI / 16), 256, 0, stream>>>(xconv, dts, BCbuf, A_logs, Ds, ysb);
  k5_combine<<<BB * (LL / 8), 256, 0, stream>>>(ysb, zbuf, out_norm_g, out_norm_b, out_proj_w,
                                                input, skip_scale, ln2_g, ln2_b, xres, ln2b);
  k6_conv1<<<BB * HH, 256, 0, stream>>>(ln2b, cab_w1, cab_b1, t1b);
  k7_conv2<<<BB * HH, 256, 0, stream>>>(t1b, cab_w2, cab_b2, t2b);
  k8_mean<<<BB * CC, 256, 0, stream>>>(t2b, smean);
  k9_ca<<<BB, 128, 0, stream>>>(smean, ca_w1, ca_b1, ca_w2, ca_b2, s3);
  k10_final<<<BB * CC, 256, 0, stream>>>(xres, t2b, s3, skip_scale2, (float*)d_out);
}

// Round 2
// 1120.502 us; speedup vs baseline: 2.5471x; 2.5471x over previous
//
#include <hip/hip_runtime.h>
#include <math.h>

// Problem constants
#define BB 2
#define CC 128
#define HH 64
#define WW 64
#define LL 4096      // H*W
#define DI 256       // D_INNER
#define NS 16        // D_STATE
#define KK 4         // scan directions
#define OC1 42       // C // 3

// Chunked scan parameters
#define NC 32        // chunks per sequence
#define CL 128       // steps per chunk (LL/NC)

__device__ __forceinline__ float sigmoidf_(float x) { return 1.f / (1.f + __expf(-x)); }
__device__ __forceinline__ float siluf_(float x)    { return x * sigmoidf_(x); }
__device__ __forceinline__ float softplusf_(float x){ return x > 20.f ? x : log1pf(__expf(x)); }

__device__ __forceinline__ int scan_pos(int k, int i) {
  if (k == 0) return i;
  if (k == 1) return ((i & 63) << 6) | (i >> 6);
  if (k == 2) return (LL - 1) - i;
  int j = (LL - 1) - i;
  return ((j & 63) << 6) | (j >> 6);
}

// ---------------------------------------------------------------------------
// K1: LN1 over C at each (b,p), then in_proj (512x128). 16 positions/block.
// ---------------------------------------------------------------------------
__global__ __launch_bounds__(256) void k1_ln_inproj(
    const float* __restrict__ inp, const float* __restrict__ g, const float* __restrict__ b,
    const float* __restrict__ wproj, float* __restrict__ xcin, float* __restrict__ zbuf) {
  __shared__ float sx[16][132];
  __shared__ float smu[16], srs[16];
  const int tid = threadIdx.x;
  const int bb = blockIdx.x >> 8;
  const int pbase = (blockIdx.x & 255) << 4;

  for (int idx = tid; idx < 16 * CC; idx += 256) {
    int c = idx >> 4, pl = idx & 15;
    sx[pl][c] = inp[((size_t)bb * CC + c) * LL + pbase + pl];
  }
  __syncthreads();
  {
    int pl = tid >> 4, j = tid & 15;
    float s = 0.f, s2 = 0.f;
    for (int c = j; c < CC; c += 16) { float v = sx[pl][c]; s += v; s2 += v * v; }
#pragma unroll
    for (int m = 1; m < 16; m <<= 1) { s += __shfl_xor(s, m); s2 += __shfl_xor(s2, m); }
    if (j == 0) {
      float mu = s * (1.f / CC);
      smu[pl] = mu;
      srs[pl] = rsqrtf(s2 * (1.f / CC) - mu * mu + 1e-5f);
    }
  }
  __syncthreads();
  for (int idx = tid; idx < 16 * CC; idx += 256) {
    int c = idx >> 4, pl = idx & 15;
    sx[pl][c] = (sx[pl][c] - smu[pl]) * srs[pl] * g[c] + b[c];
  }
  __syncthreads();

  float acc0[16], acc1[16];
#pragma unroll
  for (int pl = 0; pl < 16; pl++) { acc0[pl] = 0.f; acc1[pl] = 0.f; }
  const float4* w0 = (const float4*)(wproj + (size_t)tid * CC);
  const float4* w1 = (const float4*)(wproj + (size_t)(tid + 256) * CC);
  for (int i = 0; i < CC / 4; i++) {
    float4 wa = w0[i], wb = w1[i];
#pragma unroll
    for (int pl = 0; pl < 16; pl++) {
      float4 xv = *(const float4*)&sx[pl][i * 4];
      acc0[pl] += wa.x * xv.x + wa.y * xv.y + wa.z * xv.z + wa.w * xv.w;
      acc1[pl] += wb.x * xv.x + wb.y * xv.y + wb.z * xv.z + wb.w * xv.w;
    }
  }
#pragma unroll
  for (int pl = 0; pl < 16; pl++) {
    size_t base = ((size_t)bb * LL + pbase + pl) * DI + tid;
    xcin[base] = acc0[pl];
    zbuf[base] = acc1[pl];
  }
}

// ---------------------------------------------------------------------------
// K2: depthwise 3x3 conv + bias + silu.
// ---------------------------------------------------------------------------
__global__ __launch_bounds__(256) void k2_dwconv(
    const float* __restrict__ xcin, const float* __restrict__ cw, const float* __restrict__ cb,
    float* __restrict__ xconv) {
  const int p = blockIdx.x & (LL - 1);
  const int bb = blockIdx.x >> 12;
  const int hh = p >> 6, ww = p & 63;
  const int d = threadIdx.x;
  float acc = cb[d];
#pragma unroll
  for (int kh = 0; kh < 3; kh++) {
    int r = hh + kh - 1;
    if (r < 0 || r >= HH) continue;
#pragma unroll
    for (int kw = 0; kw < 3; kw++) {
      int cc2 = ww + kw - 1;
      if (cc2 < 0 || cc2 >= WW) continue;
      acc += cw[d * 9 + kh * 3 + kw] * xcin[((size_t)bb * LL + r * WW + cc2) * DI + d];
    }
  }
  xconv[((size_t)bb * LL + p) * DI + d] = siluf_(acc);
}

// ---------------------------------------------------------------------------
// K3: x_proj -> dtr/Bs/Cs; dt GEMM + softplus -> dts.
// ---------------------------------------------------------------------------
__global__ __launch_bounds__(256) void k3_proj(
    const float* __restrict__ xconv, const float* __restrict__ xpw,
    const float* __restrict__ dtw, const float* __restrict__ dtb,
    float* __restrict__ BCbuf, float* __restrict__ dts) {
  __shared__ float sv[16][260];
  __shared__ float sdtr[16][KK][8];
  const int tid = threadIdx.x;
  const int bb = blockIdx.x >> 8;
  const int pbase = (blockIdx.x & 255) << 4;

  for (int idx = tid; idx < 16 * DI; idx += 256) {
    int d = idx & 255, pl = idx >> 8;
    sv[pl][d] = xconv[((size_t)bb * LL + pbase + pl) * DI + d];
  }
  __syncthreads();

  if (tid < 160) {
    int k = tid / 40, c = tid % 40;
    const float4* wp = (const float4*)(xpw + ((size_t)k * 40 + c) * DI);
    float acc[16];
#pragma unroll
    for (int pl = 0; pl < 16; pl++) acc[pl] = 0.f;
    for (int i = 0; i < DI / 4; i++) {
      float4 wv = wp[i];
#pragma unroll
      for (int pl = 0; pl < 16; pl++) {
        float4 xv = *(const float4*)&sv[pl][i * 4];
        acc[pl] += wv.x * xv.x + wv.y * xv.y + wv.z * xv.z + wv.w * xv.w;
      }
    }
#pragma unroll
    for (int pl = 0; pl < 16; pl++) {
      if (c < 8) sdtr[pl][k][c] = acc[pl];
      else BCbuf[(((size_t)bb * KK + k) * LL + pbase + pl) * 32 + (c - 8)] = acc[pl];
    }
  }
  __syncthreads();

  for (int k = 0; k < KK; k++) {
    const float4* wr = (const float4*)(dtw + ((size_t)k * DI + tid) * 8);
    float4 wv0 = wr[0], wv1 = wr[1];
    float base = dtb[k * DI + tid];
#pragma unroll 4
    for (int pl = 0; pl < 16; pl++) {
      const float* dr = sdtr[pl][k];
      float acc = base + wv0.x * dr[0] + wv0.y * dr[1] + wv0.z * dr[2] + wv0.w * dr[3]
                       + wv1.x * dr[4] + wv1.y * dr[5] + wv1.z * dr[6] + wv1.w * dr[7];
      dts[(((size_t)bb * KK + k) * LL + pbase + pl) * DI + tid] = softplusf_(acc);
    }
  }
}

// ---------------------------------------------------------------------------
// K4a: chunked scan phase 1 — per-chunk (A_c = prod dA, B_c = h_end | h_in=0).
// grid = B*K*16*NC blocks; lane = (dl,n).
// ---------------------------------------------------------------------------
__global__ __launch_bounds__(256) void k4a_chunk(
    const float* __restrict__ xconv, const float* __restrict__ dts,
    const float* __restrict__ BCbuf, const float* __restrict__ A_logs,
    float* __restrict__ csA, float* __restrict__ csB) {
  const int tid = threadIdx.x;
  const int n = tid & 15, dl = tid >> 4;
  const int chunk = blockIdx.x & (NC - 1);
  const int dg = (blockIdx.x >> 5) & 15;
  const int k = (blockIdx.x >> 9) & 3;
  const int bb = blockIdx.x >> 11;
  const int d = dg * 16 + dl;

  const float a = -__expf(A_logs[((size_t)k * DI + d) * NS + n]);
  const float* dts_p = dts + ((size_t)(bb * KK + k)) * LL * DI + d;
  const float* bc_p  = BCbuf + ((size_t)(bb * KK + k)) * LL * 32 + n;
  const float* x_p   = xconv + (size_t)bb * LL * DI + d;

  float Ap = 1.f, Bc = 0.f;
  const int base = chunk * CL;
#pragma unroll 4
  for (int ii = 0; ii < CL; ii++) {
    int pos = scan_pos(k, base + ii);
    float dt = dts_p[(size_t)pos * DI];
    float xv = x_p[(size_t)pos * DI];
    float Bv = bc_p[pos * 32];
    float dA = __expf(dt * a);
    Ap *= dA;
    Bc = dA * Bc + (dt * xv) * Bv;
  }
  size_t e = ((size_t)(((bb * KK + k) * 16 + dg) * NC) + chunk) * 256 + tid;
  csA[e] = Ap;
  csB[e] = Bc;
}

// ---------------------------------------------------------------------------
// K4b: scan the NC chunk summaries per sequence -> h_in per chunk.
// grid = B*K*16 = 128 blocks; lane tid = (dl,n) element.
// ---------------------------------------------------------------------------
__global__ __launch_bounds__(256) void k4b_scanchunks(
    const float* __restrict__ csA, const float* __restrict__ csB, float* __restrict__ hin) {
  const int tid = threadIdx.x;
  const size_t base = (size_t)blockIdx.x * NC * 256 + tid;
  float H = 0.f;
#pragma unroll 8
  for (int c = 0; c < NC; c++) {
    size_t e = base + (size_t)c * 256;
    float A = csA[e], Bv = csB[e];
    hin[e] = H;
    H = A * H + Bv;
  }
}

// ---------------------------------------------------------------------------
// K4c: chunked scan phase 3 — rerun recurrence from h_in, emit y.
// ---------------------------------------------------------------------------
__global__ __launch_bounds__(256) void k4c_scan(
    const float* __restrict__ xconv, const float* __restrict__ dts,
    const float* __restrict__ BCbuf, const float* __restrict__ A_logs,
    const float* __restrict__ Ds, const float* __restrict__ hin,
    float* __restrict__ ys) {
  const int tid = threadIdx.x;
  const int n = tid & 15, dl = tid >> 4;
  const int chunk = blockIdx.x & (NC - 1);
  const int dg = (blockIdx.x >> 5) & 15;
  const int k = (blockIdx.x >> 9) & 3;
  const int bb = blockIdx.x >> 11;
  const int d = dg * 16 + dl;

  const float a = -__expf(A_logs[((size_t)k * DI + d) * NS + n]);
  const float Dd = Ds[k * DI + d];
  const float* dts_p = dts + ((size_t)(bb * KK + k)) * LL * DI + d;
  const float* bc_p  = BCbuf + ((size_t)(bb * KK + k)) * LL * 32;
  const float* x_p   = xconv + (size_t)bb * LL * DI + d;
  float* ys_p = ys + ((size_t)(bb * KK + k)) * LL * DI + d;

  float h = hin[((size_t)(((bb * KK + k) * 16 + dg) * NC) + chunk) * 256 + tid];
  const int base = chunk * CL;
#pragma unroll 4
  for (int ii = 0; ii < CL; ii++) {
    int pos = scan_pos(k, base + ii);
    float dt = dts_p[(size_t)pos * DI];
    float xv = x_p[(size_t)pos * DI];
    float Bv = bc_p[pos * 32 + n];
    float Cv = bc_p[pos * 32 + 16 + n];
    h = __expf(dt * a) * h + (dt * xv) * Bv;
    float t = h * Cv;
    t += __shfl_xor(t, 1);
    t += __shfl_xor(t, 2);
    t += __shfl_xor(t, 4);
    t += __shfl_xor(t, 8);
    if (n == 0) ys_p[(size_t)pos * DI] = t + xv * Dd;
  }
}

// ---------------------------------------------------------------------------
// K5: sum 4 directions, out_norm LN, * silu(z), out_proj, skip; LN2 -> NCHW.
// ---------------------------------------------------------------------------
__global__ __launch_bounds__(256) void k5_combine(
    const float* __restrict__ ys, const float* __restrict__ zbuf,
    const float* __restrict__ ong, const float* __restrict__ onb,
    const float* __restrict__ opw, const float* __restrict__ inp,
    const float* __restrict__ sk, const float* __restrict__ g2, const float* __restrict__ b2,
    float* __restrict__ xres, float* __restrict__ ln2) {
  __shared__ float sy[8][260];
  __shared__ float sr[8][132];
  __shared__ float smu[8], srs[8];
  const int tid = threadIdx.x;
  const int bb = blockIdx.x >> 9;
  const int pbase = (blockIdx.x & 511) << 3;

  for (int idx = tid; idx < 8 * DI; idx += 256) {
    int d = idx & 255, pl = idx >> 8;
    size_t o0 = (((size_t)bb * KK + 0) * LL + pbase + pl) * DI + d;
    const size_t st = (size_t)LL * DI;
    sy[pl][d] = ys[o0] + ys[o0 + st] + ys[o0 + 2 * st] + ys[o0 + 3 * st];
  }
  __syncthreads();
  {
    int pl = tid >> 5, j = tid & 31;
    float s = 0.f, s2 = 0.f;
    for (int d = j; d < DI; d += 32) { float v = sy[pl][d]; s += v; s2 += v * v; }
#pragma unroll
    for (int m = 1; m < 32; m <<= 1) { s += __shfl_xor(s, m); s2 += __shfl_xor(s2, m); }
    if (j == 0) {
      float mu = s * (1.f / DI);
      smu[pl] = mu;
      srs[pl] = rsqrtf(s2 * (1.f / DI) - mu * mu + 1e-5f);
    }
  }
  __syncthreads();
  for (int idx = tid; idx < 8 * DI; idx += 256) {
    int d = idx & 255, pl = idx >> 8;
    float zv = zbuf[((size_t)bb * LL + pbase + pl) * DI + d];
    sy[pl][d] = ((sy[pl][d] - smu[pl]) * srs[pl] * ong[d] + onb[d]) * siluf_(zv);
  }
  __syncthreads();
  {
    const int c = tid & 127, plg = tid >> 7;
    float acc[4] = {0.f, 0.f, 0.f, 0.f};
    const float4* wr = (const float4*)(opw + (size_t)c * DI);
    for (int i = 0; i < DI / 4; i++) {
      float4 wv = wr[i];
#pragma unroll
      for (int q = 0; q < 4; q++) {
        float4 xv = *(const float4*)&sy[plg + 2 * q][i * 4];
        acc[q] += wv.x * xv.x + wv.y * xv.y + wv.z * xv.z + wv.w * xv.w;
      }
    }
#pragma unroll
    for (int q = 0; q < 4; q++) {
      int pl = plg + 2 * q;
      int p = pbase + pl;
      float r = inp[((size_t)bb * CC + c) * LL + p] * sk[c] + acc[q];
      xres[((size_t)bb * LL + p) * CC + c] = r;
      sr[pl][c] = r;
    }
  }
  __syncthreads();
  {
    int pl = tid >> 5, j = tid & 31;
    float s = 0.f, s2 = 0.f;
    for (int c = j; c < CC; c += 32) { float v = sr[pl][c]; s += v; s2 += v * v; }
#pragma unroll
    for (int m = 1; m < 32; m <<= 1) { s += __shfl_xor(s, m); s2 += __shfl_xor(s2, m); }
    if (j == 0) {
      float mu = s * (1.f / CC);
      smu[pl] = mu;
      srs[pl] = rsqrtf(s2 * (1.f / CC) - mu * mu + 1e-5f);
    }
  }
  __syncthreads();
  for (int idx = tid; idx < 8 * CC; idx += 256) {
    int pl = idx & 7, c = idx >> 3;
    ln2[((size_t)bb * CC + c) * LL + pbase + pl] =
        (sr[pl][c] - smu[pl]) * srs[pl] * g2[c] + b2[c];
  }
}

// ---------------------------------------------------------------------------
// K6: CAB conv1 3x3 (42 x 128) + exact GELU.
// ---------------------------------------------------------------------------
__global__ __launch_bounds__(256) void k6_conv1(
    const float* __restrict__ ln2, const float* __restrict__ w1, const float* __restrict__ b1,
    float* __restrict__ t1) {
  __shared__ float sIn[16][3][68];
  const int tid = threadIdx.x;
  const int bb = blockIdx.x >> 6;
  const int hh = blockIdx.x & 63;
  const int wl = tid & 63, ocg = tid >> 6;
  float acc[11];
#pragma unroll
  for (int j = 0; j < 11; j++) acc[j] = 0.f;

  for (int icc = 0; icc < 8; icc++) {
    for (int idx = tid; idx < 16 * 3 * 66; idx += 256) {
      int wcol = idx % 66; int t = idx / 66; int kh = t % 3; int ic = t / 3;
      int r = hh + kh - 1, cc2 = wcol - 1;
      float v = 0.f;
      if (r >= 0 && r < HH && cc2 >= 0 && cc2 < WW)
        v = ln2[((size_t)bb * CC + icc * 16 + ic) * LL + r * WW + cc2];
      sIn[ic][kh][wcol] = v;
    }
    __syncthreads();
    for (int ic = 0; ic < 16; ic++) {
#pragma unroll
      for (int kh = 0; kh < 3; kh++) {
#pragma unroll
        for (int kw = 0; kw < 3; kw++) {
          float xv = sIn[ic][kh][wl + kw];
#pragma unroll
          for (int j = 0; j < 11; j++) {
            int oc = ocg + 4 * j;
            if (oc < OC1)
              acc[j] += w1[((size_t)oc * CC + icc * 16 + ic) * 9 + kh * 3 + kw] * xv;
          }
        }
      }
    }
    __syncthreads();
  }
#pragma unroll
  for (int j = 0; j < 11; j++) {
    int oc = ocg + 4 * j;
    if (oc < OC1) {
      float x = acc[j] + b1[oc];
      t1[((size_t)bb * OC1 + oc) * LL + hh * WW + wl] =
          0.5f * x * (1.f + erff(x * 0.70710678118654752f));
    }
  }
}

// ---------------------------------------------------------------------------
// K7: CAB conv2 3x3 (128 x 42) + bias.
// ---------------------------------------------------------------------------
__global__ __launch_bounds__(256) void k7_conv2(
    const float* __restrict__ t1, const float* __restrict__ w2, const float* __restrict__ b2,
    float* __restrict__ t2) {
  __shared__ float sIn[14][3][68];
  const int tid = threadIdx.x;
  const int bb = blockIdx.x >> 6;
  const int hh = blockIdx.x & 63;
  const int wl = tid & 63, ocg = tid >> 6;
  float acc[32];
#pragma unroll
  for (int j = 0; j < 32; j++) acc[j] = 0.f;

  for (int icc = 0; icc < 3; icc++) {
    for (int idx = tid; idx < 14 * 3 * 66; idx += 256) {
      int wcol = idx % 66; int t = idx / 66; int kh = t % 3; int ic = t / 3;
      int r = hh + kh - 1, cc2 = wcol - 1;
      float v = 0.f;
      if (r >= 0 && r < HH && cc2 >= 0 && cc2 < WW)
        v = t1[((size_t)bb * OC1 + icc * 14 + ic) * LL + r * WW + cc2];
      sIn[ic][kh][wcol] = v;
    }
    __syncthreads();
    for (int ic = 0; ic < 14; ic++) {
#pragma unroll
      for (int kh = 0; kh < 3; kh++) {
#pragma unroll
        for (int kw = 0; kw < 3; kw++) {
          float xv = sIn[ic][kh][wl + kw];
#pragma unroll
          for (int j = 0; j < 32; j++)
            acc[j] += w2[((size_t)(ocg + 4 * j) * OC1 + icc * 14 + ic) * 9 + kh * 3 + kw] * xv;
        }
      }
    }
    __syncthreads();
  }
#pragma unroll
  for (int j = 0; j < 32; j++) {
    int oc = ocg + 4 * j;
    t2[((size_t)bb * CC + oc) * LL + hh * WW + wl] = acc[j] + b2[oc];
  }
}

// ---------------------------------------------------------------------------
// K8: per-(b,c) mean of t2 over L.
// ---------------------------------------------------------------------------
__global__ __launch_bounds__(256) void k8_mean(const float* __restrict__ t2,
                                               float* __restrict__ smean) {
  __shared__ float red[4];
  const int bc = blockIdx.x;
  const float* src = t2 + (size_t)bc * LL;
  float s = 0.f;
  for (int i = threadIdx.x; i < LL; i += 256) s += src[i];
#pragma unroll
  for (int m = 1; m < 64; m <<= 1) s += __shfl_xor(s, m);
  if ((threadIdx.x & 63) == 0) red[threadIdx.x >> 6] = s;
  __syncthreads();
  if (threadIdx.x == 0) smean[bc] = (red[0] + red[1] + red[2] + red[3]) * (1.f / LL);
}

// ---------------------------------------------------------------------------
// K9: channel attention MLP.
// ---------------------------------------------------------------------------
__global__ __launch_bounds__(128) void k9_ca(
    const float* __restrict__ smean, const float* __restrict__ w1, const float* __restrict__ b1,
    const float* __restrict__ w2, const float* __restrict__ b2, float* __restrict__ s3) {
  __shared__ float sm[128];
  __shared__ float mid[4];
  const int tid = threadIdx.x;
  const int bb = blockIdx.x;
  sm[tid] = smean[bb * CC + tid];
  __syncthreads();
  if (tid < 4) {
    float a = b1[tid];
    for (int c = 0; c < CC; c++) a += w1[tid * CC + c] * sm[c];
    mid[tid] = fmaxf(a, 0.f);
  }
  __syncthreads();
  float a = b2[tid];
#pragma unroll
  for (int m = 0; m < 4; m++) a += w2[tid * 4 + m] * mid[m];
  s3[bb * CC + tid] = sigmoidf_(a);
}

// ---------------------------------------------------------------------------
// K10: final combine.
// ---------------------------------------------------------------------------
__global__ __launch_bounds__(256) void k10_final(
    const float* __restrict__ xres, const float* __restrict__ t2,
    const float* __restrict__ s3, const float* __restrict__ sk2,
    float* __restrict__ out) {
  const int bc = blockIdx.x;
  const int bb = bc >> 7, c = bc & 127;
  const float ss = sk2[c], sv = s3[bc];
  const float* t2r = t2 + (size_t)bc * LL;
  float* outr = out + (size_t)bc * LL;
  for (int i = threadIdx.x; i < LL; i += 256)
    outr[i] = xres[((size_t)bb * LL + i) * CC + c] * ss + t2r[i] * sv;
}

// ---------------------------------------------------------------------------

extern "C" void kernel_launch(void* const* d_in, const int* in_sizes, int n_in,
                              void* d_out, int out_size, void* d_ws, size_t ws_size,
                              hipStream_t stream) {
  const float* input      = (const float*)d_in[0];
  const float* ln1_g      = (const float*)d_in[1];
  const float* ln1_b      = (const float*)d_in[2];
  const float* skip_scale = (const float*)d_in[3];
  const float* skip_scale2= (const float*)d_in[4];
  const float* ln2_g      = (const float*)d_in[5];
  const float* ln2_b      = (const float*)d_in[6];
  const float* in_proj_w  = (const float*)d_in[7];
  const float* conv_w     = (const float*)d_in[8];
  const float* conv_b     = (const float*)d_in[9];
  const float* x_proj_w   = (const float*)d_in[10];
  const float* dt_w       = (const float*)d_in[11];
  const float* dt_b       = (const float*)d_in[12];
  const float* A_logs     = (const float*)d_in[13];
  const float* Ds         = (const float*)d_in[14];
  const float* out_norm_g = (const float*)d_in[15];
  const float* out_norm_b = (const float*)d_in[16];
  const float* out_proj_w = (const float*)d_in[17];
  const float* cab_w1     = (const float*)d_in[18];
  const float* cab_b1     = (const float*)d_in[19];
  const float* cab_w2     = (const float*)d_in[20];
  const float* cab_b2     = (const float*)d_in[21];
  const float* ca_w1      = (const float*)d_in[22];
  const float* ca_b1      = (const float*)d_in[23];
  const float* ca_w2      = (const float*)d_in[24];
  const float* ca_b2      = (const float*)d_in[25];

  float* ws = (float*)d_ws;
  float* xcin  = ws;                                   // B*L*256
  float* zbuf  = xcin + (size_t)BB * LL * DI;          // B*L*256
  float* xconv = zbuf + (size_t)BB * LL * DI;          // B*L*256
  float* BCbuf = xconv + (size_t)BB * LL * DI;         // B*4*L*32
  float* dts   = BCbuf + (size_t)BB * KK * LL * 32;    // B*4*L*256
  float* ysb   = dts + (size_t)BB * KK * LL * DI;      // B*4*L*256
  float* xres  = ysb + (size_t)BB * KK * LL * DI;      // B*L*128
  float* ln2b  = xres + (size_t)BB * LL * CC;          // B*128*L
  float* t1b   = ln2b + (size_t)BB * CC * LL;          // B*42*L
  float* t2b   = t1b + (size_t)BB * OC1 * LL;          // B*128*L
  float* smean = t2b + (size_t)BB * CC * LL;           // B*128
  float* s3    = smean + BB * CC;                      // B*128
  // chunked-scan state: 3 x (128*NC*256) floats = 3 x 4 MB
  float* csA   = s3 + BB * CC;
  float* csB   = csA + (size_t)BB * KK * 16 * NC * 256;
  float* hin   = csB + (size_t)BB * KK * 16 * NC * 256;

  k1_ln_inproj<<<BB * (LL / 16), 256, 0, stream>>>(input, ln1_g, ln1_b, in_proj_w, xcin, zbuf);
  k2_dwconv<<<BB * LL, 256, 0, stream>>>(xcin, conv_w, conv_b, xconv);
  k3_proj<<<BB * (LL / 16), 256, 0, stream>>>(xconv, x_proj_w, dt_w, dt_b, BCbuf, dts);
  k4a_chunk<<<BB * KK * 16 * NC, 256, 0, stream>>>(xconv, dts, BCbuf, A_logs, csA, csB);
  k4b_scanchunks<<<BB * KK * 16, 256, 0, stream>>>(csA, csB, hin);
  k4c_scan<<<BB * KK * 16 * NC, 256, 0, stream>>>(xconv, dts, BCbuf, A_logs, Ds, hin, ysb);
  k5_combine<<<BB * (LL / 8), 256, 0, stream>>>(ysb, zbuf, out_norm_g, out_norm_b, out_proj_w,
                                                input, skip_scale, ln2_g, ln2_b, xres, ln2b);
  k6_conv1<<<BB * HH, 256, 0, stream>>>(ln2b, cab_w1, cab_b1, t1b);
  k7_conv2<<<BB * HH, 256, 0, stream>>>(t1b, cab_w2, cab_b2, t2b);
  k8_mean<<<BB * CC, 256, 0, stream>>>(t2b, smean);
  k9_ca<<<BB, 128, 0, stream>>>(smean, ca_w1, ca_b1, ca_w2, ca_b2, s3);
  k10_final<<<BB * CC, 256, 0, stream>>>(xres, t2b, s3, skip_scale2, (float*)d_out);
}

// Round 4
// 456.529 us; speedup vs baseline: 6.2517x; 2.4544x over previous
//
#include <hip/hip_runtime.h>
#include <math.h>

// Problem constants
#define BB 2
#define CC 128
#define HH 64
#define WW 64
#define LL 4096      // H*W
#define DI 256       // D_INNER
#define NS 16        // D_STATE
#define KK 4         // scan directions
#define OC1 42       // C // 3

// Chunked scan parameters
#define NC 32        // chunks per sequence
#define CL 128       // steps per chunk (LL/NC)

__device__ __forceinline__ float sigmoidf_(float x) { return 1.f / (1.f + __expf(-x)); }
__device__ __forceinline__ float siluf_(float x)    { return x * sigmoidf_(x); }
__device__ __forceinline__ float softplusf_(float x){ return x > 20.f ? x : log1pf(__expf(x)); }

__device__ __forceinline__ int scan_pos(int k, int i) {
  if (k == 0) return i;
  if (k == 1) return ((i & 63) << 6) | (i >> 6);
  if (k == 2) return (LL - 1) - i;
  int j = (LL - 1) - i;
  return ((j & 63) << 6) | (j >> 6);
}

// ---------------------------------------------------------------------------
// K1: LN1 over C at each (b,p), then in_proj (512x128). 16 positions/block.
// ---------------------------------------------------------------------------
__global__ __launch_bounds__(256) void k1_ln_inproj(
    const float* __restrict__ inp, const float* __restrict__ g, const float* __restrict__ b,
    const float* __restrict__ wproj, float* __restrict__ xcin, float* __restrict__ zbuf) {
  __shared__ float sx[16][132];
  __shared__ float smu[16], srs[16];
  const int tid = threadIdx.x;
  const int bb = blockIdx.x >> 8;
  const int pbase = (blockIdx.x & 255) << 4;

  for (int idx = tid; idx < 16 * CC; idx += 256) {
    int c = idx >> 4, pl = idx & 15;
    sx[pl][c] = inp[((size_t)bb * CC + c) * LL + pbase + pl];
  }
  __syncthreads();
  {
    int pl = tid >> 4, j = tid & 15;
    float s = 0.f, s2 = 0.f;
    for (int c = j; c < CC; c += 16) { float v = sx[pl][c]; s += v; s2 += v * v; }
#pragma unroll
    for (int m = 1; m < 16; m <<= 1) { s += __shfl_xor(s, m); s2 += __shfl_xor(s2, m); }
    if (j == 0) {
      float mu = s * (1.f / CC);
      smu[pl] = mu;
      srs[pl] = rsqrtf(s2 * (1.f / CC) - mu * mu + 1e-5f);
    }
  }
  __syncthreads();
  for (int idx = tid; idx < 16 * CC; idx += 256) {
    int c = idx >> 4, pl = idx & 15;
    sx[pl][c] = (sx[pl][c] - smu[pl]) * srs[pl] * g[c] + b[c];
  }
  __syncthreads();

  float acc0[16], acc1[16];
#pragma unroll
  for (int pl = 0; pl < 16; pl++) { acc0[pl] = 0.f; acc1[pl] = 0.f; }
  const float4* w0 = (const float4*)(wproj + (size_t)tid * CC);
  const float4* w1 = (const float4*)(wproj + (size_t)(tid + 256) * CC);
  for (int i = 0; i < CC / 4; i++) {
    float4 wa = w0[i], wb = w1[i];
#pragma unroll
    for (int pl = 0; pl < 16; pl++) {
      float4 xv = *(const float4*)&sx[pl][i * 4];
      acc0[pl] += wa.x * xv.x + wa.y * xv.y + wa.z * xv.z + wa.w * xv.w;
      acc1[pl] += wb.x * xv.x + wb.y * xv.y + wb.z * xv.z + wb.w * xv.w;
    }
  }
#pragma unroll
  for (int pl = 0; pl < 16; pl++) {
    size_t base = ((size_t)bb * LL + pbase + pl) * DI + tid;
    xcin[base] = acc0[pl];
    zbuf[base] = acc1[pl];
  }
}

// ---------------------------------------------------------------------------
// K2: depthwise 3x3 conv + bias + silu.
// ---------------------------------------------------------------------------
__global__ __launch_bounds__(256) void k2_dwconv(
    const float* __restrict__ xcin, const float* __restrict__ cw, const float* __restrict__ cb,
    float* __restrict__ xconv) {
  const int p = blockIdx.x & (LL - 1);
  const int bb = blockIdx.x >> 12;
  const int hh = p >> 6, ww = p & 63;
  const int d = threadIdx.x;
  float acc = cb[d];
#pragma unroll
  for (int kh = 0; kh < 3; kh++) {
    int r = hh + kh - 1;
    if (r < 0 || r >= HH) continue;
#pragma unroll
    for (int kw = 0; kw < 3; kw++) {
      int cc2 = ww + kw - 1;
      if (cc2 < 0 || cc2 >= WW) continue;
      acc += cw[d * 9 + kh * 3 + kw] * xcin[((size_t)bb * LL + r * WW + cc2) * DI + d];
    }
  }
  xconv[((size_t)bb * LL + p) * DI + d] = siluf_(acc);
}

// ---------------------------------------------------------------------------
// K3: x_proj -> dtr/Bs/Cs; dt GEMM + softplus -> dts.
// ---------------------------------------------------------------------------
__global__ __launch_bounds__(256) void k3_proj(
    const float* __restrict__ xconv, const float* __restrict__ xpw,
    const float* __restrict__ dtw, const float* __restrict__ dtb,
    float* __restrict__ BCbuf, float* __restrict__ dts) {
  __shared__ float sv[16][260];
  __shared__ float sdtr[16][KK][8];
  const int tid = threadIdx.x;
  const int bb = blockIdx.x >> 8;
  const int pbase = (blockIdx.x & 255) << 4;

  for (int idx = tid; idx < 16 * DI; idx += 256) {
    int d = idx & 255, pl = idx >> 8;
    sv[pl][d] = xconv[((size_t)bb * LL + pbase + pl) * DI + d];
  }
  __syncthreads();

  if (tid < 160) {
    int k = tid / 40, c = tid % 40;
    const float4* wp = (const float4*)(xpw + ((size_t)k * 40 + c) * DI);
    float acc[16];
#pragma unroll
    for (int pl = 0; pl < 16; pl++) acc[pl] = 0.f;
    for (int i = 0; i < DI / 4; i++) {
      float4 wv = wp[i];
#pragma unroll
      for (int pl = 0; pl < 16; pl++) {
        float4 xv = *(const float4*)&sv[pl][i * 4];
        acc[pl] += wv.x * xv.x + wv.y * xv.y + wv.z * xv.z + wv.w * xv.w;
      }
    }
#pragma unroll
    for (int pl = 0; pl < 16; pl++) {
      if (c < 8) sdtr[pl][k][c] = acc[pl];
      else BCbuf[(((size_t)bb * KK + k) * LL + pbase + pl) * 32 + (c - 8)] = acc[pl];
    }
  }
  __syncthreads();

  for (int k = 0; k < KK; k++) {
    const float4* wr = (const float4*)(dtw + ((size_t)k * DI + tid) * 8);
    float4 wv0 = wr[0], wv1 = wr[1];
    float base = dtb[k * DI + tid];
#pragma unroll 4
    for (int pl = 0; pl < 16; pl++) {
      const float* dr = sdtr[pl][k];
      float acc = base + wv0.x * dr[0] + wv0.y * dr[1] + wv0.z * dr[2] + wv0.w * dr[3]
                       + wv1.x * dr[4] + wv1.y * dr[5] + wv1.z * dr[6] + wv1.w * dr[7];
      dts[(((size_t)bb * KK + k) * LL + pbase + pl) * DI + tid] = softplusf_(acc);
    }
  }
}

// ---------------------------------------------------------------------------
// K4a: chunked scan phase 1 — per-chunk (A_c = prod dA, B_c = h_end | h_in=0).
// ---------------------------------------------------------------------------
__global__ __launch_bounds__(256) void k4a_chunk(
    const float* __restrict__ xconv, const float* __restrict__ dts,
    const float* __restrict__ BCbuf, const float* __restrict__ A_logs,
    float* __restrict__ csA, float* __restrict__ csB) {
  const int tid = threadIdx.x;
  const int n = tid & 15, dl = tid >> 4;
  const int chunk = blockIdx.x & (NC - 1);
  const int dg = (blockIdx.x >> 5) & 15;
  const int k = (blockIdx.x >> 9) & 3;
  const int bb = blockIdx.x >> 11;
  const int d = dg * 16 + dl;

  const float a = -__expf(A_logs[((size_t)k * DI + d) * NS + n]);
  const float* dts_p = dts + ((size_t)(bb * KK + k)) * LL * DI + d;
  const float* bc_p  = BCbuf + ((size_t)(bb * KK + k)) * LL * 32 + n;
  const float* x_p   = xconv + (size_t)bb * LL * DI + d;

  float Ap = 1.f, Bc = 0.f;
  const int base = chunk * CL;
#pragma unroll 4
  for (int ii = 0; ii < CL; ii++) {
    int pos = scan_pos(k, base + ii);
    float dt = dts_p[(size_t)pos * DI];
    float xv = x_p[(size_t)pos * DI];
    float Bv = bc_p[pos * 32];
    float dA = __expf(dt * a);
    Ap *= dA;
    Bc = dA * Bc + (dt * xv) * Bv;
  }
  size_t e = ((size_t)(((bb * KK + k) * 16 + dg) * NC) + chunk) * 256 + tid;
  csA[e] = Ap;
  csB[e] = Bc;
}

// ---------------------------------------------------------------------------
// K4b: scan the NC chunk summaries per sequence -> h_in per chunk.
// ---------------------------------------------------------------------------
__global__ __launch_bounds__(256) void k4b_scanchunks(
    const float* __restrict__ csA, const float* __restrict__ csB, float* __restrict__ hin) {
  const int tid = threadIdx.x;
  const size_t base = (size_t)blockIdx.x * NC * 256 + tid;
  float H = 0.f;
#pragma unroll 8
  for (int c = 0; c < NC; c++) {
    size_t e = base + (size_t)c * 256;
    float A = csA[e], Bv = csB[e];
    hin[e] = H;
    H = A * H + Bv;
  }
}

// ---------------------------------------------------------------------------
// K4c: chunked scan phase 3 — rerun recurrence from h_in, emit y.
// ---------------------------------------------------------------------------
__global__ __launch_bounds__(256) void k4c_scan(
    const float* __restrict__ xconv, const float* __restrict__ dts,
    const float* __restrict__ BCbuf, const float* __restrict__ A_logs,
    const float* __restrict__ Ds, const float* __restrict__ hin,
    float* __restrict__ ys) {
  const int tid = threadIdx.x;
  const int n = tid & 15, dl = tid >> 4;
  const int chunk = blockIdx.x & (NC - 1);
  const int dg = (blockIdx.x >> 5) & 15;
  const int k = (blockIdx.x >> 9) & 3;
  const int bb = blockIdx.x >> 11;
  const int d = dg * 16 + dl;

  const float a = -__expf(A_logs[((size_t)k * DI + d) * NS + n]);
  const float Dd = Ds[k * DI + d];
  const float* dts_p = dts + ((size_t)(bb * KK + k)) * LL * DI + d;
  const float* bc_p  = BCbuf + ((size_t)(bb * KK + k)) * LL * 32;
  const float* x_p   = xconv + (size_t)bb * LL * DI + d;
  float* ys_p = ys + ((size_t)(bb * KK + k)) * LL * DI + d;

  float h = hin[((size_t)(((bb * KK + k) * 16 + dg) * NC) + chunk) * 256 + tid];
  const int base = chunk * CL;
#pragma unroll 4
  for (int ii = 0; ii < CL; ii++) {
    int pos = scan_pos(k, base + ii);
    float dt = dts_p[(size_t)pos * DI];
    float xv = x_p[(size_t)pos * DI];
    float Bv = bc_p[pos * 32 + n];
    float Cv = bc_p[pos * 32 + 16 + n];
    h = __expf(dt * a) * h + (dt * xv) * Bv;
    float t = h * Cv;
    t += __shfl_xor(t, 1);
    t += __shfl_xor(t, 2);
    t += __shfl_xor(t, 4);
    t += __shfl_xor(t, 8);
    if (n == 0) ys_p[(size_t)pos * DI] = t + xv * Dd;
  }
}

// ---------------------------------------------------------------------------
// K5: sum 4 directions, out_norm LN, * silu(z), out_proj, skip; LN2 -> NCHW.
// ---------------------------------------------------------------------------
__global__ __launch_bounds__(256) void k5_combine(
    const float* __restrict__ ys, const float* __restrict__ zbuf,
    const float* __restrict__ ong, const float* __restrict__ onb,
    const float* __restrict__ opw, const float* __restrict__ inp,
    const float* __restrict__ sk, const float* __restrict__ g2, const float* __restrict__ b2,
    float* __restrict__ xres, float* __restrict__ ln2) {
  __shared__ float sy[8][260];
  __shared__ float sr[8][132];
  __shared__ float smu[8], srs[8];
  const int tid = threadIdx.x;
  const int bb = blockIdx.x >> 9;
  const int pbase = (blockIdx.x & 511) << 3;

  for (int idx = tid; idx < 8 * DI; idx += 256) {
    int d = idx & 255, pl = idx >> 8;
    size_t o0 = (((size_t)bb * KK + 0) * LL + pbase + pl) * DI + d;
    const size_t st = (size_t)LL * DI;
    sy[pl][d] = ys[o0] + ys[o0 + st] + ys[o0 + 2 * st] + ys[o0 + 3 * st];
  }
  __syncthreads();
  {
    int pl = tid >> 5, j = tid & 31;
    float s = 0.f, s2 = 0.f;
    for (int d = j; d < DI; d += 32) { float v = sy[pl][d]; s += v; s2 += v * v; }
#pragma unroll
    for (int m = 1; m < 32; m <<= 1) { s += __shfl_xor(s, m); s2 += __shfl_xor(s2, m); }
    if (j == 0) {
      float mu = s * (1.f / DI);
      smu[pl] = mu;
      srs[pl] = rsqrtf(s2 * (1.f / DI) - mu * mu + 1e-5f);
    }
  }
  __syncthreads();
  for (int idx = tid; idx < 8 * DI; idx += 256) {
    int d = idx & 255, pl = idx >> 8;
    float zv = zbuf[((size_t)bb * LL + pbase + pl) * DI + d];
    sy[pl][d] = ((sy[pl][d] - smu[pl]) * srs[pl] * ong[d] + onb[d]) * siluf_(zv);
  }
  __syncthreads();
  {
    const int c = tid & 127, plg = tid >> 7;
    float acc[4] = {0.f, 0.f, 0.f, 0.f};
    const float4* wr = (const float4*)(opw + (size_t)c * DI);
    for (int i = 0; i < DI / 4; i++) {
      float4 wv = wr[i];
#pragma unroll
      for (int q = 0; q < 4; q++) {
        float4 xv = *(const float4*)&sy[plg + 2 * q][i * 4];
        acc[q] += wv.x * xv.x + wv.y * xv.y + wv.z * xv.z + wv.w * xv.w;
      }
    }
#pragma unroll
    for (int q = 0; q < 4; q++) {
      int pl = plg + 2 * q;
      int p = pbase + pl;
      float r = inp[((size_t)bb * CC + c) * LL + p] * sk[c] + acc[q];
      xres[((size_t)bb * LL + p) * CC + c] = r;
      sr[pl][c] = r;
    }
  }
  __syncthreads();
  {
    int pl = tid >> 5, j = tid & 31;
    float s = 0.f, s2 = 0.f;
    for (int c = j; c < CC; c += 32) { float v = sr[pl][c]; s += v; s2 += v * v; }
#pragma unroll
    for (int m = 1; m < 32; m <<= 1) { s += __shfl_xor(s, m); s2 += __shfl_xor(s2, m); }
    if (j == 0) {
      float mu = s * (1.f / CC);
      smu[pl] = mu;
      srs[pl] = rsqrtf(s2 * (1.f / CC) - mu * mu + 1e-5f);
    }
  }
  __syncthreads();
  for (int idx = tid; idx < 8 * CC; idx += 256) {
    int pl = idx & 7, c = idx >> 3;
    ln2[((size_t)bb * CC + c) * LL + pbase + pl] =
        (sr[pl][c] - smu[pl]) * srs[pl] * g2[c] + b2[c];
  }
}

// ---------------------------------------------------------------------------
// K6a: CAB conv1 partials. K-split over input channels (8 chunks of 16).
// grid = bb(2) x h4(16) x icq(8) = 256 blocks, 256 threads.
// ---------------------------------------------------------------------------
__global__ __launch_bounds__(256) void k6a_conv1(
    const float* __restrict__ ln2, const float* __restrict__ w1,
    float* __restrict__ pc1) {
  __shared__ float sIn[16][6][68];   // 16 ic x 6 rows x 66 cols (pad 68)
  __shared__ float sw[16 * 9 * OC1]; // [(i*9+kk)*42 + oc]
  const int tid = threadIdx.x;
  const int icq = blockIdx.x & 7;
  const int h4  = (blockIdx.x >> 3) & 15;
  const int bb  = blockIdx.x >> 7;
  const int icb = icq * 16;

  for (int idx = tid; idx < 16 * 6 * 66; idx += 256) {
    int i = idx / 396, rem = idx % 396;
    int rr = rem / 66, j = rem % 66;
    int r = h4 * 4 + rr - 1, c2 = j - 1;
    float v = 0.f;
    if (r >= 0 && r < HH && c2 >= 0 && c2 < WW)
      v = ln2[((size_t)bb * CC + icb + i) * LL + r * WW + c2];
    sIn[i][rr][j] = v;
  }
  for (int idx = tid; idx < OC1 * 16 * 9; idx += 256) {
    int oc = idx / 144, rem = idx % 144;
    int i = rem / 9, kk = rem % 9;
    sw[(i * 9 + kk) * OC1 + oc] = w1[((size_t)oc * CC + icb + i) * 9 + kk];
  }
  __syncthreads();

  const int wq = tid & 7, hq = (tid >> 3) & 3, ocg = tid >> 5;
  float acc[6][8];
#pragma unroll
  for (int q = 0; q < 6; q++)
#pragma unroll
    for (int ww = 0; ww < 8; ww++) acc[q][ww] = 0.f;

  for (int i = 0; i < 16; i++) {
    float xin[3][10];
#pragma unroll
    for (int kh = 0; kh < 3; kh++)
#pragma unroll
      for (int j = 0; j < 10; j++) xin[kh][j] = sIn[i][hq + kh][wq * 8 + j];
#pragma unroll
    for (int q = 0; q < 6; q++) {
      int oc = ocg + 8 * q;
      if (oc >= OC1) break;
      float wv[9];
#pragma unroll
      for (int kk = 0; kk < 9; kk++) wv[kk] = sw[(i * 9 + kk) * OC1 + oc];
#pragma unroll
      for (int kh = 0; kh < 3; kh++)
#pragma unroll
        for (int kw = 0; kw < 3; kw++)
#pragma unroll
          for (int ww = 0; ww < 8; ww++)
            acc[q][ww] += wv[kh * 3 + kw] * xin[kh][ww + kw];
    }
  }

  const int hrow = h4 * 4 + hq;
#pragma unroll
  for (int q = 0; q < 6; q++) {
    int oc = ocg + 8 * q;
    if (oc >= OC1) break;
    float* dst = pc1 + (((size_t)icq * BB + bb) * OC1 + oc) * LL + hrow * WW + wq * 8;
    *(float4*)dst       = make_float4(acc[q][0], acc[q][1], acc[q][2], acc[q][3]);
    *(float4*)(dst + 4) = make_float4(acc[q][4], acc[q][5], acc[q][6], acc[q][7]);
  }
}

// ---------------------------------------------------------------------------
// K6b: reduce 8 partials + bias + exact GELU -> t1. grid = BB*42 blocks.
// ---------------------------------------------------------------------------
__global__ __launch_bounds__(256) void k6b_reduce(
    const float* __restrict__ pc1, const float* __restrict__ b1,
    float* __restrict__ t1) {
  const int oc = blockIdx.x % OC1;
  const int bb = blockIdx.x / OC1;
  const float bias = b1[oc];
  const size_t st = (size_t)BB * OC1 * LL;
  const float* src = pc1 + ((size_t)bb * OC1 + oc) * LL;
  float* dst = t1 + ((size_t)bb * OC1 + oc) * LL;
  for (int i = threadIdx.x; i < LL / 4; i += 256) {
    float4 s = ((const float4*)src)[i];
#pragma unroll
    for (int icq = 1; icq < 8; icq++) {
      float4 v = *(const float4*)(src + (size_t)icq * st + i * 4);
      s.x += v.x; s.y += v.y; s.z += v.z; s.w += v.w;
    }
    float r[4] = {s.x + bias, s.y + bias, s.z + bias, s.w + bias};
#pragma unroll
    for (int q = 0; q < 4; q++)
      r[q] = 0.5f * r[q] * (1.f + erff(r[q] * 0.70710678118654752f));
    ((float4*)dst)[i] = make_float4(r[0], r[1], r[2], r[3]);
  }
}

// ---------------------------------------------------------------------------
// K7: CAB conv2 (128 oc x 42 ic x 3x3) + bias -> t2.
// grid = bb(2) x h2(32) x ocq(4) = 256 blocks, 256 threads.
// ---------------------------------------------------------------------------
__global__ __launch_bounds__(256) void k7_conv2(
    const float* __restrict__ t1, const float* __restrict__ w2, const float* __restrict__ b2,
    float* __restrict__ t2) {
  __shared__ float sIn[21][4][68];
  __shared__ float sw[21 * 9 * 32];  // [(i*9+kk)*32 + oc_local]
  const int tid = threadIdx.x;
  const int ocq = blockIdx.x & 3;
  const int h2  = (blockIdx.x >> 2) & 31;
  const int bb  = blockIdx.x >> 7;

  const int wq = tid & 7, hq = (tid >> 3) & 1, ocg = tid >> 4;
  float acc[2][8];
#pragma unroll
  for (int q = 0; q < 2; q++)
#pragma unroll
    for (int ww = 0; ww < 8; ww++) acc[q][ww] = 0.f;

  for (int ch = 0; ch < 2; ch++) {
    const int icb = ch * 21;
    __syncthreads();
    for (int idx = tid; idx < 21 * 4 * 66; idx += 256) {
      int i = idx / 264, rem = idx % 264;
      int rr = rem / 66, j = rem % 66;
      int r = h2 * 2 + rr - 1, c2 = j - 1;
      float v = 0.f;
      if (r >= 0 && r < HH && c2 >= 0 && c2 < WW)
        v = t1[((size_t)bb * OC1 + icb + i) * LL + r * WW + c2];
      sIn[i][rr][j] = v;
    }
    for (int idx = tid; idx < 32 * 21 * 9; idx += 256) {
      int ol = idx / 189, rem = idx % 189;
      int i = rem / 9, kk = rem % 9;
      sw[(i * 9 + kk) * 32 + ol] = w2[((size_t)(ocq * 32 + ol) * OC1 + icb + i) * 9 + kk];
    }
    __syncthreads();

    for (int i = 0; i < 21; i++) {
      float xin[3][10];
#pragma unroll
      for (int kh = 0; kh < 3; kh++)
#pragma unroll
        for (int j = 0; j < 10; j++) xin[kh][j] = sIn[i][hq + kh][wq * 8 + j];
#pragma unroll
      for (int q = 0; q < 2; q++) {
        int ol = ocg + 16 * q;
        float wv[9];
#pragma unroll
        for (int kk = 0; kk < 9; kk++) wv[kk] = sw[(i * 9 + kk) * 32 + ol];
#pragma unroll
        for (int kh = 0; kh < 3; kh++)
#pragma unroll
          for (int kw = 0; kw < 3; kw++)
#pragma unroll
            for (int ww = 0; ww < 8; ww++)
              acc[q][ww] += wv[kh * 3 + kw] * xin[kh][ww + kw];
      }
    }
  }

  const int hrow = h2 * 2 + hq;
#pragma unroll
  for (int q = 0; q < 2; q++) {
    int oc = ocq * 32 + ocg + 16 * q;
    float bias = b2[oc];
    float* dst = t2 + ((size_t)bb * CC + oc) * LL + hrow * WW + wq * 8;
    *(float4*)dst       = make_float4(acc[q][0] + bias, acc[q][1] + bias,
                                      acc[q][2] + bias, acc[q][3] + bias);
    *(float4*)(dst + 4) = make_float4(acc[q][4] + bias, acc[q][5] + bias,
                                      acc[q][6] + bias, acc[q][7] + bias);
  }
}

// ---------------------------------------------------------------------------
// K8: per-(b,c) mean of t2 over L.
// ---------------------------------------------------------------------------
__global__ __launch_bounds__(256) void k8_mean(const float* __restrict__ t2,
                                               float* __restrict__ smean) {
  __shared__ float red[4];
  const int bc = blockIdx.x;
  const float* src = t2 + (size_t)bc * LL;
  float s = 0.f;
  for (int i = threadIdx.x; i < LL; i += 256) s += src[i];
#pragma unroll
  for (int m = 1; m < 64; m <<= 1) s += __shfl_xor(s, m);
  if ((threadIdx.x & 63) == 0) red[threadIdx.x >> 6] = s;
  __syncthreads();
  if (threadIdx.x == 0) smean[bc] = (red[0] + red[1] + red[2] + red[3]) * (1.f / LL);
}

// ---------------------------------------------------------------------------
// K9: channel attention MLP.
// ---------------------------------------------------------------------------
__global__ __launch_bounds__(128) void k9_ca(
    const float* __restrict__ smean, const float* __restrict__ w1, const float* __restrict__ b1,
    const float* __restrict__ w2, const float* __restrict__ b2, float* __restrict__ s3) {
  __shared__ float sm[128];
  __shared__ float mid[4];
  const int tid = threadIdx.x;
  const int bb = blockIdx.x;
  sm[tid] = smean[bb * CC + tid];
  __syncthreads();
  if (tid < 4) {
    float a = b1[tid];
    for (int c = 0; c < CC; c++) a += w1[tid * CC + c] * sm[c];
    mid[tid] = fmaxf(a, 0.f);
  }
  __syncthreads();
  float a = b2[tid];
#pragma unroll
  for (int m = 0; m < 4; m++) a += w2[tid * 4 + m] * mid[m];
  s3[bb * CC + tid] = sigmoidf_(a);
}

// ---------------------------------------------------------------------------
// K10: final combine.
// ---------------------------------------------------------------------------
__global__ __launch_bounds__(256) void k10_final(
    const float* __restrict__ xres, const float* __restrict__ t2,
    const float* __restrict__ s3, const float* __restrict__ sk2,
    float* __restrict__ out) {
  const int bc = blockIdx.x;
  const int bb = bc >> 7, c = bc & 127;
  const float ss = sk2[c], sv = s3[bc];
  const float* t2r = t2 + (size_t)bc * LL;
  float* outr = out + (size_t)bc * LL;
  for (int i = threadIdx.x; i < LL; i += 256)
    outr[i] = xres[((size_t)bb * LL + i) * CC + c] * ss + t2r[i] * sv;
}

// ---------------------------------------------------------------------------

extern "C" void kernel_launch(void* const* d_in, const int* in_sizes, int n_in,
                              void* d_out, int out_size, void* d_ws, size_t ws_size,
                              hipStream_t stream) {
  const float* input      = (const float*)d_in[0];
  const float* ln1_g      = (const float*)d_in[1];
  const float* ln1_b      = (const float*)d_in[2];
  const float* skip_scale = (const float*)d_in[3];
  const float* skip_scale2= (const float*)d_in[4];
  const float* ln2_g      = (const float*)d_in[5];
  const float* ln2_b      = (const float*)d_in[6];
  const float* in_proj_w  = (const float*)d_in[7];
  const float* conv_w     = (const float*)d_in[8];
  const float* conv_b     = (const float*)d_in[9];
  const float* x_proj_w   = (const float*)d_in[10];
  const float* dt_w       = (const float*)d_in[11];
  const float* dt_b       = (const float*)d_in[12];
  const float* A_logs     = (const float*)d_in[13];
  const float* Ds         = (const float*)d_in[14];
  const float* out_norm_g = (const float*)d_in[15];
  const float* out_norm_b = (const float*)d_in[16];
  const float* out_proj_w = (const float*)d_in[17];
  const float* cab_w1     = (const float*)d_in[18];
  const float* cab_b1     = (const float*)d_in[19];
  const float* cab_w2     = (const float*)d_in[20];
  const float* cab_b2     = (const float*)d_in[21];
  const float* ca_w1      = (const float*)d_in[22];
  const float* ca_b1      = (const float*)d_in[23];
  const float* ca_w2      = (const float*)d_in[24];
  const float* ca_b2      = (const float*)d_in[25];

  float* ws = (float*)d_ws;
  float* xcin  = ws;                                   // B*L*256
  float* zbuf  = xcin + (size_t)BB * LL * DI;          // B*L*256
  float* xconv = zbuf + (size_t)BB * LL * DI;          // B*L*256
  float* BCbuf = xconv + (size_t)BB * LL * DI;         // B*4*L*32
  float* dts   = BCbuf + (size_t)BB * KK * LL * 32;    // B*4*L*256
  float* ysb   = dts + (size_t)BB * KK * LL * DI;      // B*4*L*256
  float* xres  = ysb + (size_t)BB * KK * LL * DI;      // B*L*128
  float* ln2b  = xres + (size_t)BB * LL * CC;          // B*128*L
  float* t1b   = ln2b + (size_t)BB * CC * LL;          // B*42*L
  float* t2b   = t1b + (size_t)BB * OC1 * LL;          // B*128*L
  float* smean = t2b + (size_t)BB * CC * LL;           // B*128
  float* s3    = smean + BB * CC;                      // B*128
  float* csA   = s3 + BB * CC;                         // 128*NC*256
  float* csB   = csA + (size_t)BB * KK * 16 * NC * 256;
  float* hin   = csB + (size_t)BB * KK * 16 * NC * 256;
  // conv1 partials (8 chunks x B x 42 x L = 2.75M floats) alias dead ysb
  float* pc1   = ysb;  // ysb is dead after k5; pc1 written by k6a after k5

  k1_ln_inproj<<<BB * (LL / 16), 256, 0, stream>>>(input, ln1_g, ln1_b, in_proj_w, xcin, zbuf);
  k2_dwconv<<<BB * LL, 256, 0, stream>>>(xcin, conv_w, conv_b, xconv);
  k3_proj<<<BB * (LL / 16), 256, 0, stream>>>(xconv, x_proj_w, dt_w, dt_b, BCbuf, dts);
  k4a_chunk<<<BB * KK * 16 * NC, 256, 0, stream>>>(xconv, dts, BCbuf, A_logs, csA, csB);
  k4b_scanchunks<<<BB * KK * 16, 256, 0, stream>>>(csA, csB, hin);
  k4c_scan<<<BB * KK * 16 * NC, 256, 0, stream>>>(xconv, dts, BCbuf, A_logs, Ds, hin, ysb);
  k5_combine<<<BB * (LL / 8), 256, 0, stream>>>(ysb, zbuf, out_norm_g, out_norm_b, out_proj_w,
                                                input, skip_scale, ln2_g, ln2_b, xres, ln2b);
  k6a_conv1<<<BB * 16 * 8, 256, 0, stream>>>(ln2b, cab_w1, pc1);
  k6b_reduce<<<BB * OC1, 256, 0, stream>>>(pc1, cab_b1, t1b);
  k7_conv2<<<BB * 32 * 4, 256, 0, stream>>>(t1b, cab_w2, cab_b2, t2b);
  k8_mean<<<BB * CC, 256, 0, stream>>>(t2b, smean);
  k9_ca<<<BB, 128, 0, stream>>>(smean, ca_w1, ca_b1, ca_w2, ca_b2, s3);
  k10_final<<<BB * CC, 256, 0, stream>>>(xres, t2b, s3, skip_scale2, (float*)d_out);
}

// Round 5
// 337.000 us; speedup vs baseline: 8.4691x; 1.3547x over previous
//
#include <hip/hip_runtime.h>
#include <math.h>

// Problem constants
#define BB 2
#define CC 128
#define HH 64
#define WW 64
#define LL 4096      // H*W
#define DI 256       // D_INNER
#define NS 16        // D_STATE
#define KK 4         // scan directions
#define OC1 42       // C // 3

// Chunked scan parameters
#define NC 64        // chunks per sequence
#define CL 64        // steps per chunk (LL/NC)

__device__ __forceinline__ float sigmoidf_(float x) { return 1.f / (1.f + __expf(-x)); }
__device__ __forceinline__ float siluf_(float x)    { return x * sigmoidf_(x); }
__device__ __forceinline__ float softplusf_(float x){ return x > 20.f ? x : log1pf(__expf(x)); }

__device__ __forceinline__ int scan_pos(int k, int i) {
  if (k == 0) return i;
  if (k == 1) return ((i & 63) << 6) | (i >> 6);
  if (k == 2) return (LL - 1) - i;
  int j = (LL - 1) - i;
  return ((j & 63) << 6) | (j >> 6);
}

// ---------------------------------------------------------------------------
// K1: LN1 over C at each (b,p), then in_proj (512x128). 16 positions/block.
// ---------------------------------------------------------------------------
__global__ __launch_bounds__(256) void k1_ln_inproj(
    const float* __restrict__ inp, const float* __restrict__ g, const float* __restrict__ b,
    const float* __restrict__ wproj, float* __restrict__ xcin, float* __restrict__ zbuf) {
  __shared__ float sx[16][132];
  __shared__ float smu[16], srs[16];
  const int tid = threadIdx.x;
  const int bb = blockIdx.x >> 8;
  const int pbase = (blockIdx.x & 255) << 4;

  for (int idx = tid; idx < 16 * CC; idx += 256) {
    int c = idx >> 4, pl = idx & 15;
    sx[pl][c] = inp[((size_t)bb * CC + c) * LL + pbase + pl];
  }
  __syncthreads();
  {
    int pl = tid >> 4, j = tid & 15;
    float s = 0.f, s2 = 0.f;
    for (int c = j; c < CC; c += 16) { float v = sx[pl][c]; s += v; s2 += v * v; }
#pragma unroll
    for (int m = 1; m < 16; m <<= 1) { s += __shfl_xor(s, m); s2 += __shfl_xor(s2, m); }
    if (j == 0) {
      float mu = s * (1.f / CC);
      smu[pl] = mu;
      srs[pl] = rsqrtf(s2 * (1.f / CC) - mu * mu + 1e-5f);
    }
  }
  __syncthreads();
  for (int idx = tid; idx < 16 * CC; idx += 256) {
    int c = idx >> 4, pl = idx & 15;
    sx[pl][c] = (sx[pl][c] - smu[pl]) * srs[pl] * g[c] + b[c];
  }
  __syncthreads();

  float acc0[16], acc1[16];
#pragma unroll
  for (int pl = 0; pl < 16; pl++) { acc0[pl] = 0.f; acc1[pl] = 0.f; }
  const float4* w0 = (const float4*)(wproj + (size_t)tid * CC);
  const float4* w1 = (const float4*)(wproj + (size_t)(tid + 256) * CC);
  for (int i = 0; i < CC / 4; i++) {
    float4 wa = w0[i], wb = w1[i];
#pragma unroll
    for (int pl = 0; pl < 16; pl++) {
      float4 xv = *(const float4*)&sx[pl][i * 4];
      acc0[pl] += wa.x * xv.x + wa.y * xv.y + wa.z * xv.z + wa.w * xv.w;
      acc1[pl] += wb.x * xv.x + wb.y * xv.y + wb.z * xv.z + wb.w * xv.w;
    }
  }
#pragma unroll
  for (int pl = 0; pl < 16; pl++) {
    size_t base = ((size_t)bb * LL + pbase + pl) * DI + tid;
    xcin[base] = acc0[pl];
    zbuf[base] = acc1[pl];
  }
}

// ---------------------------------------------------------------------------
// K2: depthwise 3x3 conv + bias + silu.
// ---------------------------------------------------------------------------
__global__ __launch_bounds__(256) void k2_dwconv(
    const float* __restrict__ xcin, const float* __restrict__ cw, const float* __restrict__ cb,
    float* __restrict__ xconv) {
  const int p = blockIdx.x & (LL - 1);
  const int bb = blockIdx.x >> 12;
  const int hh = p >> 6, ww = p & 63;
  const int d = threadIdx.x;
  float acc = cb[d];
#pragma unroll
  for (int kh = 0; kh < 3; kh++) {
    int r = hh + kh - 1;
    if (r < 0 || r >= HH) continue;
#pragma unroll
    for (int kw = 0; kw < 3; kw++) {
      int cc2 = ww + kw - 1;
      if (cc2 < 0 || cc2 >= WW) continue;
      acc += cw[d * 9 + kh * 3 + kw] * xcin[((size_t)bb * LL + r * WW + cc2) * DI + d];
    }
  }
  xconv[((size_t)bb * LL + p) * DI + d] = siluf_(acc);
}

// ---------------------------------------------------------------------------
// K3: x_proj -> dtr/Bs/Cs; dt GEMM + softplus -> dts.
// ---------------------------------------------------------------------------
__global__ __launch_bounds__(256) void k3_proj(
    const float* __restrict__ xconv, const float* __restrict__ xpw,
    const float* __restrict__ dtw, const float* __restrict__ dtb,
    float* __restrict__ BCbuf, float* __restrict__ dts) {
  __shared__ float sv[16][260];
  __shared__ float sdtr[16][KK][8];
  const int tid = threadIdx.x;
  const int bb = blockIdx.x >> 8;
  const int pbase = (blockIdx.x & 255) << 4;

  for (int idx = tid; idx < 16 * DI; idx += 256) {
    int d = idx & 255, pl = idx >> 8;
    sv[pl][d] = xconv[((size_t)bb * LL + pbase + pl) * DI + d];
  }
  __syncthreads();

  if (tid < 160) {
    int k = tid / 40, c = tid % 40;
    const float4* wp = (const float4*)(xpw + ((size_t)k * 40 + c) * DI);
    float acc[16];
#pragma unroll
    for (int pl = 0; pl < 16; pl++) acc[pl] = 0.f;
    for (int i = 0; i < DI / 4; i++) {
      float4 wv = wp[i];
#pragma unroll
      for (int pl = 0; pl < 16; pl++) {
        float4 xv = *(const float4*)&sv[pl][i * 4];
        acc[pl] += wv.x * xv.x + wv.y * xv.y + wv.z * xv.z + wv.w * xv.w;
      }
    }
#pragma unroll
    for (int pl = 0; pl < 16; pl++) {
      if (c < 8) sdtr[pl][k][c] = acc[pl];
      else BCbuf[(((size_t)bb * KK + k) * LL + pbase + pl) * 32 + (c - 8)] = acc[pl];
    }
  }
  __syncthreads();

  for (int k = 0; k < KK; k++) {
    const float4* wr = (const float4*)(dtw + ((size_t)k * DI + tid) * 8);
    float4 wv0 = wr[0], wv1 = wr[1];
    float base = dtb[k * DI + tid];
#pragma unroll 4
    for (int pl = 0; pl < 16; pl++) {
      const float* dr = sdtr[pl][k];
      float acc = base + wv0.x * dr[0] + wv0.y * dr[1] + wv0.z * dr[2] + wv0.w * dr[3]
                       + wv1.x * dr[4] + wv1.y * dr[5] + wv1.z * dr[6] + wv1.w * dr[7];
      dts[(((size_t)bb * KK + k) * LL + pbase + pl) * DI + tid] = softplusf_(acc);
    }
  }
}

// ---------------------------------------------------------------------------
// K4a: chunked scan phase 1. Thread owns d with all 16 n-states in registers.
// grid = BB*KK*NC = 512 blocks x 256 threads(d). BC staged in LDS.
// Computes per-chunk (Ap[n] = prod dA, Bc[n] = h_end | h_in=0).
// ---------------------------------------------------------------------------
__global__ __launch_bounds__(256) void k4a_chunk(
    const float* __restrict__ xconv, const float* __restrict__ dts,
    const float* __restrict__ BCbuf, const float* __restrict__ A_logs,
    float* __restrict__ csA, float* __restrict__ csB) {
  __shared__ float sBC[CL][32];
  const int d = threadIdx.x;
  const int chunk = blockIdx.x & (NC - 1);
  const int k = (blockIdx.x >> 6) & 3;
  const int bb = blockIdx.x >> 8;
  const int bk = bb * KK + k;
  const int base = chunk * CL;

  for (int idx = d; idx < CL * 32; idx += 256) {
    int ii = idx >> 5, j = idx & 31;
    int pos = scan_pos(k, base + ii);
    sBC[ii][j] = BCbuf[((size_t)bk * LL + pos) * 32 + j];
  }
  float a[NS];
#pragma unroll
  for (int n = 0; n < NS; n++)
    a[n] = -__expf(A_logs[((size_t)k * DI + d) * NS + n]);
  __syncthreads();

  const float* dts_p = dts + (size_t)bk * LL * DI + d;
  const float* x_p   = xconv + (size_t)bb * LL * DI + d;

  float Ap[NS], Bc[NS];
#pragma unroll
  for (int n = 0; n < NS; n++) { Ap[n] = 1.f; Bc[n] = 0.f; }

#pragma unroll 2
  for (int ii = 0; ii < CL; ii++) {
    int pos = scan_pos(k, base + ii);
    float dt = dts_p[(size_t)pos * DI];
    float xv = x_p[(size_t)pos * DI];
    float dtx = dt * xv;
#pragma unroll
    for (int n = 0; n < NS; n++) {
      float dA = __expf(dt * a[n]);
      Ap[n] *= dA;
      Bc[n] = dA * Bc[n] + dtx * sBC[ii][n];
    }
  }
  size_t e = ((size_t)(bk * NC + chunk) * NS) * DI + d;
#pragma unroll
  for (int n = 0; n < NS; n++) {
    csA[e + (size_t)n * DI] = Ap[n];
    csB[e + (size_t)n * DI] = Bc[n];
  }
}

// ---------------------------------------------------------------------------
// K4b: scan NC chunk summaries -> h_in per chunk, written IN-PLACE into csA.
// grid = BB*KK*NS = 128 blocks x 256 threads(d).
// ---------------------------------------------------------------------------
__global__ __launch_bounds__(256) void k4b_scanchunks(
    float* csAh, const float* __restrict__ csB) {
  const int d = threadIdx.x;
  const int n = blockIdx.x & (NS - 1);
  const int bk = blockIdx.x >> 4;
  const size_t stride = (size_t)NS * DI;
  size_t e = ((size_t)bk * NC * NS + n) * DI + d;
  float H = 0.f;
  for (int c = 0; c < NC; c++) {
    float A = csAh[e];
    float Bv = csB[e];
    csAh[e] = H;          // h_in for this chunk
    H = A * H + Bv;
    e += stride;
  }
}

// ---------------------------------------------------------------------------
// K4c: chunked scan phase 3 — rerun recurrence from h_in, emit y (+ D term).
// grid = BB*KK*NC = 512 blocks x 256 threads(d).
// ---------------------------------------------------------------------------
__global__ __launch_bounds__(256) void k4c_scan(
    const float* __restrict__ xconv, const float* __restrict__ dts,
    const float* __restrict__ BCbuf, const float* __restrict__ A_logs,
    const float* __restrict__ Ds, const float* __restrict__ hin,
    float* __restrict__ ys) {
  __shared__ float sBC[CL][32];
  const int d = threadIdx.x;
  const int chunk = blockIdx.x & (NC - 1);
  const int k = (blockIdx.x >> 6) & 3;
  const int bb = blockIdx.x >> 8;
  const int bk = bb * KK + k;
  const int base = chunk * CL;

  for (int idx = d; idx < CL * 32; idx += 256) {
    int ii = idx >> 5, j = idx & 31;
    int pos = scan_pos(k, base + ii);
    sBC[ii][j] = BCbuf[((size_t)bk * LL + pos) * 32 + j];
  }
  float a[NS], h[NS];
  const size_t eh = ((size_t)(bk * NC + chunk) * NS) * DI + d;
#pragma unroll
  for (int n = 0; n < NS; n++) {
    a[n] = -__expf(A_logs[((size_t)k * DI + d) * NS + n]);
    h[n] = hin[eh + (size_t)n * DI];
  }
  const float Dd = Ds[k * DI + d];
  __syncthreads();

  const float* dts_p = dts + (size_t)bk * LL * DI + d;
  const float* x_p   = xconv + (size_t)bb * LL * DI + d;
  float* ys_p = ys + (size_t)bk * LL * DI + d;

#pragma unroll 2
  for (int ii = 0; ii < CL; ii++) {
    int pos = scan_pos(k, base + ii);
    float dt = dts_p[(size_t)pos * DI];
    float xv = x_p[(size_t)pos * DI];
    float dtx = dt * xv;
    float y = xv * Dd;
#pragma unroll
    for (int n = 0; n < NS; n++) {
      float dA = __expf(dt * a[n]);
      h[n] = dA * h[n] + dtx * sBC[ii][n];
      y += h[n] * sBC[ii][16 + n];
    }
    ys_p[(size_t)pos * DI] = y;
  }
}

// ---------------------------------------------------------------------------
// K5: sum 4 directions, out_norm LN, * silu(z), out_proj, skip; LN2 -> NCHW.
// ---------------------------------------------------------------------------
__global__ __launch_bounds__(256) void k5_combine(
    const float* __restrict__ ys, const float* __restrict__ zbuf,
    const float* __restrict__ ong, const float* __restrict__ onb,
    const float* __restrict__ opw, const float* __restrict__ inp,
    const float* __restrict__ sk, const float* __restrict__ g2, const float* __restrict__ b2,
    float* __restrict__ xres, float* __restrict__ ln2) {
  __shared__ float sy[8][260];
  __shared__ float sr[8][132];
  __shared__ float smu[8], srs[8];
  const int tid = threadIdx.x;
  const int bb = blockIdx.x >> 9;
  const int pbase = (blockIdx.x & 511) << 3;

  for (int idx = tid; idx < 8 * DI; idx += 256) {
    int d = idx & 255, pl = idx >> 8;
    size_t o0 = (((size_t)bb * KK + 0) * LL + pbase + pl) * DI + d;
    const size_t st = (size_t)LL * DI;
    sy[pl][d] = ys[o0] + ys[o0 + st] + ys[o0 + 2 * st] + ys[o0 + 3 * st];
  }
  __syncthreads();
  {
    int pl = tid >> 5, j = tid & 31;
    float s = 0.f, s2 = 0.f;
    for (int d = j; d < DI; d += 32) { float v = sy[pl][d]; s += v; s2 += v * v; }
#pragma unroll
    for (int m = 1; m < 32; m <<= 1) { s += __shfl_xor(s, m); s2 += __shfl_xor(s2, m); }
    if (j == 0) {
      float mu = s * (1.f / DI);
      smu[pl] = mu;
      srs[pl] = rsqrtf(s2 * (1.f / DI) - mu * mu + 1e-5f);
    }
  }
  __syncthreads();
  for (int idx = tid; idx < 8 * DI; idx += 256) {
    int d = idx & 255, pl = idx >> 8;
    float zv = zbuf[((size_t)bb * LL + pbase + pl) * DI + d];
    sy[pl][d] = ((sy[pl][d] - smu[pl]) * srs[pl] * ong[d] + onb[d]) * siluf_(zv);
  }
  __syncthreads();
  {
    const int c = tid & 127, plg = tid >> 7;
    float acc[4] = {0.f, 0.f, 0.f, 0.f};
    const float4* wr = (const float4*)(opw + (size_t)c * DI);
    for (int i = 0; i < DI / 4; i++) {
      float4 wv = wr[i];
#pragma unroll
      for (int q = 0; q < 4; q++) {
        float4 xv = *(const float4*)&sy[plg + 2 * q][i * 4];
        acc[q] += wv.x * xv.x + wv.y * xv.y + wv.z * xv.z + wv.w * xv.w;
      }
    }
#pragma unroll
    for (int q = 0; q < 4; q++) {
      int pl = plg + 2 * q;
      int p = pbase + pl;
      float r = inp[((size_t)bb * CC + c) * LL + p] * sk[c] + acc[q];
      xres[((size_t)bb * LL + p) * CC + c] = r;
      sr[pl][c] = r;
    }
  }
  __syncthreads();
  {
    int pl = tid >> 5, j = tid & 31;
    float s = 0.f, s2 = 0.f;
    for (int c = j; c < CC; c += 32) { float v = sr[pl][c]; s += v; s2 += v * v; }
#pragma unroll
    for (int m = 1; m < 32; m <<= 1) { s += __shfl_xor(s, m); s2 += __shfl_xor(s2, m); }
    if (j == 0) {
      float mu = s * (1.f / CC);
      smu[pl] = mu;
      srs[pl] = rsqrtf(s2 * (1.f / CC) - mu * mu + 1e-5f);
    }
  }
  __syncthreads();
  for (int idx = tid; idx < 8 * CC; idx += 256) {
    int pl = idx & 7, c = idx >> 3;
    ln2[((size_t)bb * CC + c) * LL + pbase + pl] =
        (sr[pl][c] - smu[pl]) * srs[pl] * g2[c] + b2[c];
  }
}

// ---------------------------------------------------------------------------
// K6a: CAB conv1 partials. K-split over input channels (8 chunks of 16).
// grid = bb(2) x h4(16) x icq(8) = 256 blocks, 256 threads.
// ---------------------------------------------------------------------------
__global__ __launch_bounds__(256) void k6a_conv1(
    const float* __restrict__ ln2, const float* __restrict__ w1,
    float* __restrict__ pc1) {
  __shared__ float sIn[16][6][68];   // 16 ic x 6 rows x 66 cols (pad 68)
  __shared__ float sw[16 * 9 * OC1]; // [(i*9+kk)*42 + oc]
  const int tid = threadIdx.x;
  const int icq = blockIdx.x & 7;
  const int h4  = (blockIdx.x >> 3) & 15;
  const int bb  = blockIdx.x >> 7;
  const int icb = icq * 16;

  for (int idx = tid; idx < 16 * 6 * 66; idx += 256) {
    int i = idx / 396, rem = idx % 396;
    int rr = rem / 66, j = rem % 66;
    int r = h4 * 4 + rr - 1, c2 = j - 1;
    float v = 0.f;
    if (r >= 0 && r < HH && c2 >= 0 && c2 < WW)
      v = ln2[((size_t)bb * CC + icb + i) * LL + r * WW + c2];
    sIn[i][rr][j] = v;
  }
  for (int idx = tid; idx < OC1 * 16 * 9; idx += 256) {
    int oc = idx / 144, rem = idx % 144;
    int i = rem / 9, kk = rem % 9;
    sw[(i * 9 + kk) * OC1 + oc] = w1[((size_t)oc * CC + icb + i) * 9 + kk];
  }
  __syncthreads();

  const int wq = tid & 7, hq = (tid >> 3) & 3, ocg = tid >> 5;
  float acc[6][8];
#pragma unroll
  for (int q = 0; q < 6; q++)
#pragma unroll
    for (int ww = 0; ww < 8; ww++) acc[q][ww] = 0.f;

  for (int i = 0; i < 16; i++) {
    float xin[3][10];
#pragma unroll
    for (int kh = 0; kh < 3; kh++)
#pragma unroll
      for (int j = 0; j < 10; j++) xin[kh][j] = sIn[i][hq + kh][wq * 8 + j];
#pragma unroll
    for (int q = 0; q < 6; q++) {
      int oc = ocg + 8 * q;
      if (oc >= OC1) break;
      float wv[9];
#pragma unroll
      for (int kk = 0; kk < 9; kk++) wv[kk] = sw[(i * 9 + kk) * OC1 + oc];
#pragma unroll
      for (int kh = 0; kh < 3; kh++)
#pragma unroll
        for (int kw = 0; kw < 3; kw++)
#pragma unroll
          for (int ww = 0; ww < 8; ww++)
            acc[q][ww] += wv[kh * 3 + kw] * xin[kh][ww + kw];
    }
  }

  const int hrow = h4 * 4 + hq;
#pragma unroll
  for (int q = 0; q < 6; q++) {
    int oc = ocg + 8 * q;
    if (oc >= OC1) break;
    float* dst = pc1 + (((size_t)icq * BB + bb) * OC1 + oc) * LL + hrow * WW + wq * 8;
    *(float4*)dst       = make_float4(acc[q][0], acc[q][1], acc[q][2], acc[q][3]);
    *(float4*)(dst + 4) = make_float4(acc[q][4], acc[q][5], acc[q][6], acc[q][7]);
  }
}

// ---------------------------------------------------------------------------
// K6b: reduce 8 partials + bias + exact GELU -> t1. grid = BB*42 blocks.
// ---------------------------------------------------------------------------
__global__ __launch_bounds__(256) void k6b_reduce(
    const float* __restrict__ pc1, const float* __restrict__ b1,
    float* __restrict__ t1) {
  const int oc = blockIdx.x % OC1;
  const int bb = blockIdx.x / OC1;
  const float bias = b1[oc];
  const size_t st = (size_t)BB * OC1 * LL;
  const float* src = pc1 + ((size_t)bb * OC1 + oc) * LL;
  float* dst = t1 + ((size_t)bb * OC1 + oc) * LL;
  for (int i = threadIdx.x; i < LL / 4; i += 256) {
    float4 s = ((const float4*)src)[i];
#pragma unroll
    for (int icq = 1; icq < 8; icq++) {
      float4 v = *(const float4*)(src + (size_t)icq * st + i * 4);
      s.x += v.x; s.y += v.y; s.z += v.z; s.w += v.w;
    }
    float r[4] = {s.x + bias, s.y + bias, s.z + bias, s.w + bias};
#pragma unroll
    for (int q = 0; q < 4; q++)
      r[q] = 0.5f * r[q] * (1.f + erff(r[q] * 0.70710678118654752f));
    ((float4*)dst)[i] = make_float4(r[0], r[1], r[2], r[3]);
  }
}

// ---------------------------------------------------------------------------
// K7: CAB conv2 (128 oc x 42 ic x 3x3) + bias -> t2.
// grid = bb(2) x h2(32) x ocq(4) = 256 blocks, 256 threads.
// ---------------------------------------------------------------------------
__global__ __launch_bounds__(256) void k7_conv2(
    const float* __restrict__ t1, const float* __restrict__ w2, const float* __restrict__ b2,
    float* __restrict__ t2) {
  __shared__ float sIn[21][4][68];
  __shared__ float sw[21 * 9 * 32];  // [(i*9+kk)*32 + oc_local]
  const int tid = threadIdx.x;
  const int ocq = blockIdx.x & 3;
  const int h2  = (blockIdx.x >> 2) & 31;
  const int bb  = blockIdx.x >> 7;

  const int wq = tid & 7, hq = (tid >> 3) & 1, ocg = tid >> 4;
  float acc[2][8];
#pragma unroll
  for (int q = 0; q < 2; q++)
#pragma unroll
    for (int ww = 0; ww < 8; ww++) acc[q][ww] = 0.f;

  for (int ch = 0; ch < 2; ch++) {
    const int icb = ch * 21;
    __syncthreads();
    for (int idx = tid; idx < 21 * 4 * 66; idx += 256) {
      int i = idx / 264, rem = idx % 264;
      int rr = rem / 66, j = rem % 66;
      int r = h2 * 2 + rr - 1, c2 = j - 1;
      float v = 0.f;
      if (r >= 0 && r < HH && c2 >= 0 && c2 < WW)
        v = t1[((size_t)bb * OC1 + icb + i) * LL + r * WW + c2];
      sIn[i][rr][j] = v;
    }
    for (int idx = tid; idx < 32 * 21 * 9; idx += 256) {
      int ol = idx / 189, rem = idx % 189;
      int i = rem / 9, kk = rem % 9;
      sw[(i * 9 + kk) * 32 + ol] = w2[((size_t)(ocq * 32 + ol) * OC1 + icb + i) * 9 + kk];
    }
    __syncthreads();

    for (int i = 0; i < 21; i++) {
      float xin[3][10];
#pragma unroll
      for (int kh = 0; kh < 3; kh++)
#pragma unroll
        for (int j = 0; j < 10; j++) xin[kh][j] = sIn[i][hq + kh][wq * 8 + j];
#pragma unroll
      for (int q = 0; q < 2; q++) {
        int ol = ocg + 16 * q;
        float wv[9];
#pragma unroll
        for (int kk = 0; kk < 9; kk++) wv[kk] = sw[(i * 9 + kk) * 32 + ol];
#pragma unroll
        for (int kh = 0; kh < 3; kh++)
#pragma unroll
          for (int kw = 0; kw < 3; kw++)
#pragma unroll
            for (int ww = 0; ww < 8; ww++)
              acc[q][ww] += wv[kh * 3 + kw] * xin[kh][ww + kw];
      }
    }
  }

  const int hrow = h2 * 2 + hq;
#pragma unroll
  for (int q = 0; q < 2; q++) {
    int oc = ocq * 32 + ocg + 16 * q;
    float bias = b2[oc];
    float* dst = t2 + ((size_t)bb * CC + oc) * LL + hrow * WW + wq * 8;
    *(float4*)dst       = make_float4(acc[q][0] + bias, acc[q][1] + bias,
                                      acc[q][2] + bias, acc[q][3] + bias);
    *(float4*)(dst + 4) = make_float4(acc[q][4] + bias, acc[q][5] + bias,
                                      acc[q][6] + bias, acc[q][7] + bias);
  }
}

// ---------------------------------------------------------------------------
// K8: per-(b,c) mean of t2 over L.
// ---------------------------------------------------------------------------
__global__ __launch_bounds__(256) void k8_mean(const float* __restrict__ t2,
                                               float* __restrict__ smean) {
  __shared__ float red[4];
  const int bc = blockIdx.x;
  const float* src = t2 + (size_t)bc * LL;
  float s = 0.f;
  for (int i = threadIdx.x; i < LL; i += 256) s += src[i];
#pragma unroll
  for (int m = 1; m < 64; m <<= 1) s += __shfl_xor(s, m);
  if ((threadIdx.x & 63) == 0) red[threadIdx.x >> 6] = s;
  __syncthreads();
  if (threadIdx.x == 0) smean[bc] = (red[0] + red[1] + red[2] + red[3]) * (1.f / LL);
}

// ---------------------------------------------------------------------------
// K9: channel attention MLP.
// ---------------------------------------------------------------------------
__global__ __launch_bounds__(128) void k9_ca(
    const float* __restrict__ smean, const float* __restrict__ w1, const float* __restrict__ b1,
    const float* __restrict__ w2, const float* __restrict__ b2, float* __restrict__ s3) {
  __shared__ float sm[128];
  __shared__ float mid[4];
  const int tid = threadIdx.x;
  const int bb = blockIdx.x;
  sm[tid] = smean[bb * CC + tid];
  __syncthreads();
  if (tid < 4) {
    float a = b1[tid];
    for (int c = 0; c < CC; c++) a += w1[tid * CC + c] * sm[c];
    mid[tid] = fmaxf(a, 0.f);
  }
  __syncthreads();
  float a = b2[tid];
#pragma unroll
  for (int m = 0; m < 4; m++) a += w2[tid * 4 + m] * mid[m];
  s3[bb * CC + tid] = sigmoidf_(a);
}

// ---------------------------------------------------------------------------
// K10: final combine.
// ---------------------------------------------------------------------------
__global__ __launch_bounds__(256) void k10_final(
    const float* __restrict__ xres, const float* __restrict__ t2,
    const float* __restrict__ s3, const float* __restrict__ sk2,
    float* __restrict__ out) {
  const int bc = blockIdx.x;
  const int bb = bc >> 7, c = bc & 127;
  const float ss = sk2[c], sv = s3[bc];
  const float* t2r = t2 + (size_t)bc * LL;
  float* outr = out + (size_t)bc * LL;
  for (int i = threadIdx.x; i < LL; i += 256)
    outr[i] = xres[((size_t)bb * LL + i) * CC + c] * ss + t2r[i] * sv;
}

// ---------------------------------------------------------------------------

extern "C" void kernel_launch(void* const* d_in, const int* in_sizes, int n_in,
                              void* d_out, int out_size, void* d_ws, size_t ws_size,
                              hipStream_t stream) {
  const float* input      = (const float*)d_in[0];
  const float* ln1_g      = (const float*)d_in[1];
  const float* ln1_b      = (const float*)d_in[2];
  const float* skip_scale = (const float*)d_in[3];
  const float* skip_scale2= (const float*)d_in[4];
  const float* ln2_g      = (const float*)d_in[5];
  const float* ln2_b      = (const float*)d_in[6];
  const float* in_proj_w  = (const float*)d_in[7];
  const float* conv_w     = (const float*)d_in[8];
  const float* conv_b     = (const float*)d_in[9];
  const float* x_proj_w   = (const float*)d_in[10];
  const float* dt_w       = (const float*)d_in[11];
  const float* dt_b       = (const float*)d_in[12];
  const float* A_logs     = (const float*)d_in[13];
  const float* Ds         = (const float*)d_in[14];
  const float* out_norm_g = (const float*)d_in[15];
  const float* out_norm_b = (const float*)d_in[16];
  const float* out_proj_w = (const float*)d_in[17];
  const float* cab_w1     = (const float*)d_in[18];
  const float* cab_b1     = (const float*)d_in[19];
  const float* cab_w2     = (const float*)d_in[20];
  const float* cab_b2     = (const float*)d_in[21];
  const float* ca_w1      = (const float*)d_in[22];
  const float* ca_b1      = (const float*)d_in[23];
  const float* ca_w2      = (const float*)d_in[24];
  const float* ca_b2      = (const float*)d_in[25];

  float* ws = (float*)d_ws;
  float* xcin  = ws;                                   // B*L*256
  float* zbuf  = xcin + (size_t)BB * LL * DI;          // B*L*256
  float* xconv = zbuf + (size_t)BB * LL * DI;          // B*L*256
  float* BCbuf = xconv + (size_t)BB * LL * DI;         // B*4*L*32
  float* dts   = BCbuf + (size_t)BB * KK * LL * 32;    // B*4*L*256
  float* ysb   = dts + (size_t)BB * KK * LL * DI;      // B*4*L*256
  float* xres  = ysb + (size_t)BB * KK * LL * DI;      // B*L*128
  float* ln2b  = xres + (size_t)BB * LL * CC;          // B*128*L
  float* t1b   = ln2b + (size_t)BB * CC * LL;          // B*42*L
  float* t2b   = t1b + (size_t)BB * OC1 * LL;          // B*128*L
  float* smean = t2b + (size_t)BB * CC * LL;           // B*128
  float* s3    = smean + BB * CC;                      // B*128
  // chunk-summary A (also holds h_in after k4b, in-place): B*K*NC*NS*DI floats
  float* csA   = s3 + BB * CC;
  // csB aliases ysb: csB live k4a->k4b; ysb live k4c->k5 (disjoint).
  float* csB   = ysb;
  // conv1 partials (8 x B x 42 x L) alias ysb too (dead after k5).
  float* pc1   = ysb;

  k1_ln_inproj<<<BB * (LL / 16), 256, 0, stream>>>(input, ln1_g, ln1_b, in_proj_w, xcin, zbuf);
  k2_dwconv<<<BB * LL, 256, 0, stream>>>(xcin, conv_w, conv_b, xconv);
  k3_proj<<<BB * (LL / 16), 256, 0, stream>>>(xconv, x_proj_w, dt_w, dt_b, BCbuf, dts);
  k4a_chunk<<<BB * KK * NC, 256, 0, stream>>>(xconv, dts, BCbuf, A_logs, csA, csB);
  k4b_scanchunks<<<BB * KK * NS, 256, 0, stream>>>(csA, csB);
  k4c_scan<<<BB * KK * NC, 256, 0, stream>>>(xconv, dts, BCbuf, A_logs, Ds, csA, ysb);
  k5_combine<<<BB * (LL / 8), 256, 0, stream>>>(ysb, zbuf, out_norm_g, out_norm_b, out_proj_w,
                                                input, skip_scale, ln2_g, ln2_b, xres, ln2b);
  k6a_conv1<<<BB * 16 * 8, 256, 0, stream>>>(ln2b, cab_w1, pc1);
  k6b_reduce<<<BB * OC1, 256, 0, stream>>>(pc1, cab_b1, t1b);
  k7_conv2<<<BB * 32 * 4, 256, 0, stream>>>(t1b, cab_w2, cab_b2, t2b);
  k8_mean<<<BB * CC, 256, 0, stream>>>(t2b, smean);
  k9_ca<<<BB, 128, 0, stream>>>(smean, ca_w1, ca_b1, ca_w2, ca_b2, s3);
  k10_final<<<BB * CC, 256, 0, stream>>>(xres, t2b, s3, skip_scale2, (float*)d_out);
}